// Round 1
// baseline (423.065 us; speedup 1.0000x reference)
//
#include <hip/hip_runtime.h>

#define Bd 4
#define Hd 8
#define Ld 2048
#define Dd 64
#define Ud 40
#define NTOP 40
#define NCHUNK 64
#define CSZ 32   // Ld / NCHUNK

// ---------------------------------------------------------------------------
// Kernel 1: M[b,h,q] = max_u(dot(q, k[ridx[q,u]])) - sum_u(dot)/L
// One wave (64 lanes) per query row; lane u (<40) computes one sampled dot.
// ---------------------------------------------------------------------------
__global__ void compute_M_kernel(const float* __restrict__ q,
                                 const float* __restrict__ k,
                                 const int* __restrict__ ridx,
                                 float* __restrict__ M) {
  int wave = threadIdx.x >> 6;
  int lane = threadIdx.x & 63;
  int qgroup = blockIdx.x % (Ld / 4);
  int bh = blockIdx.x / (Ld / 4);
  int b = bh >> 3, h = bh & 7;
  int qpos = qgroup * 4 + wave;

  const float4* qr = reinterpret_cast<const float4*>(
      q + (((size_t)b * Ld + qpos) * Hd + h) * Dd);

  float dot = 0.f;
  if (lane < Ud) {
    int kidx = ridx[qpos * Ud + lane];
    const float4* kr = reinterpret_cast<const float4*>(
        k + (((size_t)b * Ld + kidx) * Hd + h) * Dd);
#pragma unroll
    for (int j = 0; j < Dd / 4; ++j) {
      float4 a = qr[j];
      float4 bb = kr[j];
      dot += a.x * bb.x + a.y * bb.y + a.z * bb.z + a.w * bb.w;
    }
  }
  float mx = (lane < Ud) ? dot : -INFINITY;
  float sm = (lane < Ud) ? dot : 0.f;
#pragma unroll
  for (int off = 32; off; off >>= 1) {
    mx = fmaxf(mx, __shfl_xor(mx, off));
    sm += __shfl_xor(sm, off);
  }
  if (lane == 0) M[bh * Ld + qpos] = mx - sm * (1.0f / (float)Ld);
}

// ---------------------------------------------------------------------------
// Kernel 2: top-40 indices per (b,h) via 40 x iterative argmax in LDS.
// Ties broken toward lower index (matches jax.lax.top_k stability).
// ---------------------------------------------------------------------------
__global__ void topk_kernel(const float* __restrict__ M,
                            int* __restrict__ topIdx) {
  __shared__ float vals[Ld];
  __shared__ float rv[256];
  __shared__ int ri[256];
  int bh = blockIdx.x;
  int tid = threadIdx.x;
  for (int i = tid; i < Ld; i += 256) vals[i] = M[bh * Ld + i];
  __syncthreads();
  for (int it = 0; it < NTOP; ++it) {
    float best = -INFINITY;
    int bidx = Ld;  // sentinel larger than any real index
    for (int i = tid; i < Ld; i += 256) {
      float v = vals[i];
      if (v > best) { best = v; bidx = i; }  // first hit = lowest i per thread
    }
    rv[tid] = best;
    ri[tid] = bidx;
    __syncthreads();
    for (int s = 128; s; s >>= 1) {
      if (tid < s) {
        float v2 = rv[tid + s];
        int i2 = ri[tid + s];
        if (v2 > rv[tid] || (v2 == rv[tid] && i2 < ri[tid])) {
          rv[tid] = v2;
          ri[tid] = i2;
        }
      }
      __syncthreads();
    }
    if (tid == 0) {
      topIdx[bh * NTOP + it] = ri[0];
      vals[ri[0]] = -INFINITY;
    }
    __syncthreads();
  }
}

// ---------------------------------------------------------------------------
// Kernel 3a: per-chunk sums of V along L (chunk = CSZ timesteps).
// One wave per (b,h,chunk); lane = d.
// ---------------------------------------------------------------------------
__global__ void chunk_sums_kernel(const float* __restrict__ v,
                                  float* __restrict__ csum) {
  int blk = blockIdx.x;  // bh*NCHUNK + c
  int c = blk % NCHUNK, bh = blk / NCHUNK;
  int b = bh >> 3, h = bh & 7;
  int d = threadIdx.x;
  float s = 0.f;
  int t0 = c * CSZ;
#pragma unroll 4
  for (int j = 0; j < CSZ; ++j)
    s += v[(((size_t)b * Ld + t0 + j) * Hd + h) * Dd + d];
  csum[(size_t)blk * Dd + d] = s;
}

// ---------------------------------------------------------------------------
// Kernel 3b: exclusive scan of the NCHUNK chunk sums per (b,h,d). Tiny.
// ---------------------------------------------------------------------------
__global__ void scan_chunks_kernel(float* __restrict__ csum) {
  int bh = blockIdx.x;
  int d = threadIdx.x;
  float acc = 0.f;
  for (int c = 0; c < NCHUNK; ++c) {
    size_t i = ((size_t)bh * NCHUNK + c) * Dd + d;
    float s = csum[i];
    csum[i] = acc;
    acc += s;
  }
}

// ---------------------------------------------------------------------------
// Kernel 3c: inclusive cumsum write: out[b,t,h,d] = offset + running sum.
// ---------------------------------------------------------------------------
__global__ void cumsum_write_kernel(const float* __restrict__ v,
                                    const float* __restrict__ csum,
                                    float* __restrict__ out) {
  int blk = blockIdx.x;
  int c = blk % NCHUNK, bh = blk / NCHUNK;
  int b = bh >> 3, h = bh & 7;
  int d = threadIdx.x;
  float acc = csum[(size_t)blk * Dd + d];
  int t0 = c * CSZ;
#pragma unroll 4
  for (int j = 0; j < CSZ; ++j) {
    size_t idx = (((size_t)b * Ld + t0 + j) * Hd + h) * Dd + d;
    acc += v[idx];
    out[idx] = acc;
  }
}

// ---------------------------------------------------------------------------
// Kernel 4: for each selected query t = topIdx[b,h,u]:
//   scores[k] = 0.125 * dot(q[t], K[k])   for k <= t   (causal)
//   attn = softmax(scores); out[b,t,h,:] = attn @ V   (overwrites cumsum row)
// One block (256 thr) per (b,h,u). Scores staged in LDS (8 KB).
// ---------------------------------------------------------------------------
__global__ void attn_update_kernel(const float* __restrict__ q,
                                   const float* __restrict__ k,
                                   const float* __restrict__ v,
                                   const int* __restrict__ topIdx,
                                   float* __restrict__ out) {
  __shared__ float sc[Ld];
  __shared__ float qs[Dd];
  __shared__ float red[256];
  int tid = threadIdx.x;
  int u = blockIdx.x % NTOP;
  int bh = blockIdx.x / NTOP;
  int b = bh >> 3, h = bh & 7;
  int t = topIdx[bh * NTOP + u];

  if (tid < Dd) qs[tid] = q[(((size_t)b * Ld + t) * Hd + h) * Dd + tid];
  __syncthreads();

  int nk = t + 1;
  const float4* qv4 = reinterpret_cast<const float4*>(qs);

  // Pass 1: scores -> LDS, track local max
  float lmax = -INFINITY;
  for (int kk = tid; kk < nk; kk += 256) {
    const float4* kr = reinterpret_cast<const float4*>(
        k + (((size_t)b * Ld + kk) * Hd + h) * Dd);
    float dot = 0.f;
#pragma unroll
    for (int j = 0; j < Dd / 4; ++j) {
      float4 a = qv4[j];
      float4 bb = kr[j];
      dot += a.x * bb.x + a.y * bb.y + a.z * bb.z + a.w * bb.w;
    }
    dot *= 0.125f;  // 1/sqrt(64)
    sc[kk] = dot;
    lmax = fmaxf(lmax, dot);
  }
  red[tid] = lmax;
  __syncthreads();
  for (int s = 128; s; s >>= 1) {
    if (tid < s) red[tid] = fmaxf(red[tid], red[tid + s]);
    __syncthreads();
  }
  float m = red[0];
  __syncthreads();

  // Pass 2: exp + denom
  float lsum = 0.f;
  for (int kk = tid; kk < nk; kk += 256) {
    float p = __expf(sc[kk] - m);
    sc[kk] = p;
    lsum += p;
  }
  red[tid] = lsum;
  __syncthreads();
  for (int s = 128; s; s >>= 1) {
    if (tid < s) red[tid] += red[tid + s];
    __syncthreads();
  }
  float inv_denom = 1.0f / red[0];
  __syncthreads();

  // Pass 3: P @ V. wave w handles k = w mod 4; lane = d (coalesced V rows).
  int d = tid & 63, kg = tid >> 6;
  float acc = 0.f;
  for (int kk = kg; kk < nk; kk += 4)
    acc += sc[kk] * v[(((size_t)b * Ld + kk) * Hd + h) * Dd + d];
  red[tid] = acc;
  __syncthreads();
  if (kg == 0) {
    float r = red[d] + red[64 + d] + red[128 + d] + red[192 + d];
    out[(((size_t)b * Ld + t) * Hd + h) * Dd + d] = r * inv_denom;
  }
}

// ---------------------------------------------------------------------------
extern "C" void kernel_launch(void* const* d_in, const int* in_sizes, int n_in,
                              void* d_out, int out_size, void* d_ws,
                              size_t ws_size, hipStream_t stream) {
  const float* q = (const float*)d_in[0];
  const float* k = (const float*)d_in[1];
  const float* v = (const float*)d_in[2];
  // d_in[3] = attn_mask (unused by reference math)
  const int* ridx = (const int*)d_in[4];
  float* out = (float*)d_out;

  char* ws = (char*)d_ws;
  float* M = (float*)ws;                       // B*H*L floats      = 256 KB
  int* topIdx = (int*)(ws + 256 * 1024);       // B*H*40 ints       =   5 KB
  float* csum = (float*)(ws + 320 * 1024);     // B*H*NCHUNK*D f32  = 512 KB

  compute_M_kernel<<<Bd * Hd * (Ld / 4), 256, 0, stream>>>(q, k, ridx, M);
  topk_kernel<<<Bd * Hd, 256, 0, stream>>>(M, topIdx);
  chunk_sums_kernel<<<Bd * Hd * NCHUNK, 64, 0, stream>>>(v, csum);
  scan_chunks_kernel<<<Bd * Hd, 64, 0, stream>>>(csum);
  cumsum_write_kernel<<<Bd * Hd * NCHUNK, 64, 0, stream>>>(v, csum, out);
  attn_update_kernel<<<Bd * Hd * NTOP, 256, 0, stream>>>(q, k, v, topIdx, out);
}

// Round 2
// 315.313 us; speedup vs baseline: 1.3417x; 1.3417x over previous
//
#include <hip/hip_runtime.h>

#define Bd 4
#define Hd 8
#define Ld 2048
#define Dd 64
#define Ud 40
#define NTOP 40
#define NCHUNK 128
#define CSZ 16   // Ld / NCHUNK

#define KS 16     // k-splits for scores kernel
#define KTILE 128 // Ld / KS
#define QSTR 68   // padded LDS stride (floats) for q rows
#define KSTR 68   // padded LDS stride (floats) for k rows
#define VS 8      // k-splits for PV
#define VTILE 256 // Ld / VS

// ---------------------------------------------------------------------------
// Kernel 1: M[b,h,q] = max_u(dot(q, k[ridx[q,u]])) - sum_u(dot)/L
// One wave (64 lanes) per query row; lane u (<40) computes one sampled dot.
// ---------------------------------------------------------------------------
__global__ void compute_M_kernel(const float* __restrict__ q,
                                 const float* __restrict__ k,
                                 const int* __restrict__ ridx,
                                 float* __restrict__ M) {
  int wave = threadIdx.x >> 6;
  int lane = threadIdx.x & 63;
  int qgroup = blockIdx.x % (Ld / 4);
  int bh = blockIdx.x / (Ld / 4);
  int b = bh >> 3, h = bh & 7;
  int qpos = qgroup * 4 + wave;

  const float4* qr = reinterpret_cast<const float4*>(
      q + (((size_t)b * Ld + qpos) * Hd + h) * Dd);

  float dot = 0.f;
  if (lane < Ud) {
    int kidx = ridx[qpos * Ud + lane];
    const float4* kr = reinterpret_cast<const float4*>(
        k + (((size_t)b * Ld + kidx) * Hd + h) * Dd);
#pragma unroll
    for (int j = 0; j < Dd / 4; ++j) {
      float4 a = qr[j];
      float4 bb = kr[j];
      dot += a.x * bb.x + a.y * bb.y + a.z * bb.z + a.w * bb.w;
    }
  }
  float mx = (lane < Ud) ? dot : -INFINITY;
  float sm = (lane < Ud) ? dot : 0.f;
#pragma unroll
  for (int off = 32; off; off >>= 1) {
    mx = fmaxf(mx, __shfl_xor(mx, off));
    sm += __shfl_xor(sm, off);
  }
  if (lane == 0) M[bh * Ld + qpos] = mx - sm * (1.0f / (float)Ld);
}

// ---------------------------------------------------------------------------
// Kernel 2: top-40 indices per (b,h) via 40 x iterative argmax in LDS.
// ---------------------------------------------------------------------------
__global__ void topk_kernel(const float* __restrict__ M,
                            int* __restrict__ topIdx) {
  __shared__ float vals[Ld];
  __shared__ float rv[256];
  __shared__ int ri[256];
  int bh = blockIdx.x;
  int tid = threadIdx.x;
  for (int i = tid; i < Ld; i += 256) vals[i] = M[bh * Ld + i];
  __syncthreads();
  for (int it = 0; it < NTOP; ++it) {
    float best = -INFINITY;
    int bidx = Ld;
    for (int i = tid; i < Ld; i += 256) {
      float v = vals[i];
      if (v > best) { best = v; bidx = i; }
    }
    rv[tid] = best;
    ri[tid] = bidx;
    __syncthreads();
    for (int s = 128; s; s >>= 1) {
      if (tid < s) {
        float v2 = rv[tid + s];
        int i2 = ri[tid + s];
        if (v2 > rv[tid] || (v2 == rv[tid] && i2 < ri[tid])) {
          rv[tid] = v2;
          ri[tid] = i2;
        }
      }
      __syncthreads();
    }
    if (tid == 0) {
      topIdx[bh * NTOP + it] = ri[0];
      vals[ri[0]] = -INFINITY;
    }
    __syncthreads();
  }
}

// ---------------------------------------------------------------------------
// Kernel 3a: per-chunk sums of V along L. Block (256 thr) per (b,h,chunk).
// ---------------------------------------------------------------------------
__global__ void chunk_sums_kernel(const float* __restrict__ v,
                                  float* __restrict__ csum) {
  __shared__ float red[256];
  int blk = blockIdx.x;  // bh*NCHUNK + c
  int c = blk % NCHUNK, bh = blk / NCHUNK;
  int b = bh >> 3, h = bh & 7;
  int d = threadIdx.x & 63, jg = threadIdx.x >> 6;
  int t0 = c * CSZ;
  float s = 0.f;
#pragma unroll
  for (int j = jg; j < CSZ; j += 4)
    s += v[(((size_t)b * Ld + t0 + j) * Hd + h) * Dd + d];
  red[threadIdx.x] = s;
  __syncthreads();
  if (jg == 0)
    csum[(size_t)blk * Dd + d] = red[d] + red[64 + d] + red[128 + d] + red[192 + d];
}

// ---------------------------------------------------------------------------
// Kernel 3b: exclusive scan of the NCHUNK chunk sums per (b,h,d).
// ---------------------------------------------------------------------------
__global__ void scan_chunks_kernel(float* __restrict__ csum) {
  int bh = blockIdx.x;
  int d = threadIdx.x;
  float acc = 0.f;
#pragma unroll 8
  for (int c = 0; c < NCHUNK; ++c) {
    size_t i = ((size_t)bh * NCHUNK + c) * Dd + d;
    float s = csum[i];
    csum[i] = acc;
    acc += s;
  }
}

// ---------------------------------------------------------------------------
// Kernel 3c: inclusive cumsum write.
// ---------------------------------------------------------------------------
__global__ void cumsum_write_kernel(const float* __restrict__ v,
                                    const float* __restrict__ csum,
                                    float* __restrict__ out) {
  int blk = blockIdx.x;
  int c = blk % NCHUNK, bh = blk / NCHUNK;
  int b = bh >> 3, h = bh & 7;
  int d = threadIdx.x;
  float acc = csum[(size_t)blk * Dd + d];
  int t0 = c * CSZ;
#pragma unroll 4
  for (int j = 0; j < CSZ; ++j) {
    size_t idx = (((size_t)b * Ld + t0 + j) * Hd + h) * Dd + d;
    acc += v[idx];
    out[idx] = acc;
  }
}

// ---------------------------------------------------------------------------
// Kernel 4a: masked scaled scores for all 40 selected queries x K tile.
// Grid: bh(32) x KS(16). LDS-staged panel GEMM, 5u x 4k register tile.
// P[bh][u][k] = (k <= t_u) ? 0.125*dot(q_sel_u, K_k) : -inf
// ---------------------------------------------------------------------------
__global__ __launch_bounds__(256) void scores_kernel(
    const float* __restrict__ q, const float* __restrict__ k,
    const int* __restrict__ topIdx, float* __restrict__ P) {
  __shared__ float qs[NTOP * QSTR];
  __shared__ float ks[KTILE * KSTR];
  __shared__ int ts[NTOP];
  int tid = threadIdx.x;
  int ksplit = blockIdx.x % KS;
  int bh = blockIdx.x / KS;
  int b = bh >> 3, h = bh & 7;
  int k0 = ksplit * KTILE;

  if (tid < NTOP) ts[tid] = topIdx[bh * NTOP + tid];
  __syncthreads();

  for (int i = tid; i < NTOP * 16; i += 256) {
    int u = i >> 4, p = i & 15;
    float4 qv = reinterpret_cast<const float4*>(
        q + (((size_t)b * Ld + ts[u]) * Hd + h) * Dd)[p];
    *reinterpret_cast<float4*>(&qs[u * QSTR + p * 4]) = qv;
  }
  for (int i = tid; i < KTILE * 16; i += 256) {
    int r = i >> 4, p = i & 15;
    float4 kv = reinterpret_cast<const float4*>(
        k + (((size_t)b * Ld + k0 + r) * Hd + h) * Dd)[p];
    *reinterpret_cast<float4*>(&ks[r * KSTR + p * 4]) = kv;
  }
  __syncthreads();

  int ug = tid & 7, kg = tid >> 3;  // u base = ug*5, k base = kg*4
  int ub = ug * 5, kb = kg * 4;
  float acc[5][4] = {};
  for (int dd = 0; dd < Dd; dd += 4) {
    float4 kv[4], qv[5];
#pragma unroll
    for (int i = 0; i < 4; ++i)
      kv[i] = *reinterpret_cast<const float4*>(&ks[(kb + i) * KSTR + dd]);
#pragma unroll
    for (int i = 0; i < 5; ++i)
      qv[i] = *reinterpret_cast<const float4*>(&qs[(ub + i) * QSTR + dd]);
#pragma unroll
    for (int ui = 0; ui < 5; ++ui)
#pragma unroll
      for (int ki = 0; ki < 4; ++ki)
        acc[ui][ki] += qv[ui].x * kv[ki].x + qv[ui].y * kv[ki].y +
                       qv[ui].z * kv[ki].z + qv[ui].w * kv[ki].w;
  }

#pragma unroll
  for (int ui = 0; ui < 5; ++ui) {
    int u = ub + ui;
    int t = ts[u];
    float4 o;
    o.x = (k0 + kb + 0 <= t) ? acc[ui][0] * 0.125f : -INFINITY;
    o.y = (k0 + kb + 1 <= t) ? acc[ui][1] * 0.125f : -INFINITY;
    o.z = (k0 + kb + 2 <= t) ? acc[ui][2] * 0.125f : -INFINITY;
    o.w = (k0 + kb + 3 <= t) ? acc[ui][3] * 0.125f : -INFINITY;
    *reinterpret_cast<float4*>(&P[((size_t)bh * NTOP + u) * Ld + k0 + kb]) = o;
  }
}

// ---------------------------------------------------------------------------
// Kernel 4b: per selected row: max, exp in place, 1/denominator.
// ---------------------------------------------------------------------------
__global__ void softmax_prep_kernel(const int* __restrict__ topIdx,
                                    float* __restrict__ P,
                                    float* __restrict__ invden) {
  __shared__ float red[256];
  int row = blockIdx.x;  // bh*NTOP + u
  int t = topIdx[row];
  int nk = t + 1;
  float* pr = P + (size_t)row * Ld;
  int tid = threadIdx.x;
  float lmax = -INFINITY;
  for (int i = tid; i < nk; i += 256) lmax = fmaxf(lmax, pr[i]);
  red[tid] = lmax;
  __syncthreads();
  for (int s = 128; s; s >>= 1) {
    if (tid < s) red[tid] = fmaxf(red[tid], red[tid + s]);
    __syncthreads();
  }
  float m = red[0];
  __syncthreads();
  float lsum = 0.f;
  for (int i = tid; i < nk; i += 256) {
    float p = __expf(pr[i] - m);
    pr[i] = p;
    lsum += p;
  }
  red[tid] = lsum;
  __syncthreads();
  for (int s = 128; s; s >>= 1) {
    if (tid < s) red[tid] += red[tid + s];
    __syncthreads();
  }
  if (tid == 0) invden[row] = 1.0f / red[0];
}

// ---------------------------------------------------------------------------
// Kernel 4c: split-K partial PV: partial[row][vs][d] = sum_k P[row][k]*V[k][d]
// over k in [vs*VTILE, min(t, vs*VTILE+VTILE-1)]. Early-exit masked blocks.
// ---------------------------------------------------------------------------
__global__ void pv_partial_kernel(const float* __restrict__ v,
                                  const int* __restrict__ topIdx,
                                  const float* __restrict__ P,
                                  float* __restrict__ partial) {
  __shared__ float red[256];
  int vs = blockIdx.x % VS;
  int row = blockIdx.x / VS;  // bh*NTOP + u
  int bh = row / NTOP;
  int b = bh >> 3, h = bh & 7;
  int t = topIdx[row];
  int d = threadIdx.x & 63, kg = threadIdx.x >> 6;
  int k0 = vs * VTILE;
  float acc = 0.f;
  if (k0 <= t) {
    int kend = min(t, k0 + VTILE - 1);
    const float* pr = P + (size_t)row * Ld;
    for (int kk = k0 + kg; kk <= kend; kk += 4)
      acc += pr[kk] * v[(((size_t)b * Ld + kk) * Hd + h) * Dd + d];
  }
  red[threadIdx.x] = acc;
  __syncthreads();
  if (kg == 0)
    partial[(size_t)blockIdx.x * Dd + d] =
        red[d] + red[64 + d] + red[128 + d] + red[192 + d];
}

// ---------------------------------------------------------------------------
// Kernel 4d: combine partials, normalize, scatter-overwrite output rows.
// ---------------------------------------------------------------------------
__global__ void pv_combine_kernel(const float* __restrict__ partial,
                                  const float* __restrict__ invden,
                                  const int* __restrict__ topIdx,
                                  float* __restrict__ out) {
  int row = blockIdx.x;
  int d = threadIdx.x;  // 64
  int bh = row / NTOP;
  int b = bh >> 3, h = bh & 7;
  int t = topIdx[row];
  float s = 0.f;
#pragma unroll
  for (int vs = 0; vs < VS; ++vs) s += partial[((size_t)row * VS + vs) * Dd + d];
  out[(((size_t)b * Ld + t) * Hd + h) * Dd + d] = s * invden[row];
}

// ---------------------------------------------------------------------------
// Fallback attention kernel (round-1 version) if ws is too small.
// ---------------------------------------------------------------------------
__global__ void attn_update_kernel(const float* __restrict__ q,
                                   const float* __restrict__ k,
                                   const float* __restrict__ v,
                                   const int* __restrict__ topIdx,
                                   float* __restrict__ out) {
  __shared__ float sc[Ld];
  __shared__ float qs[Dd];
  __shared__ float red[256];
  int tid = threadIdx.x;
  int bh = blockIdx.x / NTOP;
  int b = bh >> 3, h = bh & 7;
  int t = topIdx[blockIdx.x];

  if (tid < Dd) qs[tid] = q[(((size_t)b * Ld + t) * Hd + h) * Dd + tid];
  __syncthreads();

  int nk = t + 1;
  const float4* qv4 = reinterpret_cast<const float4*>(qs);
  float lmax = -INFINITY;
  for (int kk = tid; kk < nk; kk += 256) {
    const float4* kr = reinterpret_cast<const float4*>(
        k + (((size_t)b * Ld + kk) * Hd + h) * Dd);
    float dot = 0.f;
#pragma unroll
    for (int j = 0; j < Dd / 4; ++j) {
      float4 a = qv4[j];
      float4 bb = kr[j];
      dot += a.x * bb.x + a.y * bb.y + a.z * bb.z + a.w * bb.w;
    }
    dot *= 0.125f;
    sc[kk] = dot;
    lmax = fmaxf(lmax, dot);
  }
  red[tid] = lmax;
  __syncthreads();
  for (int s = 128; s; s >>= 1) {
    if (tid < s) red[tid] = fmaxf(red[tid], red[tid + s]);
    __syncthreads();
  }
  float m = red[0];
  __syncthreads();
  float lsum = 0.f;
  for (int kk = tid; kk < nk; kk += 256) {
    float p = __expf(sc[kk] - m);
    sc[kk] = p;
    lsum += p;
  }
  red[tid] = lsum;
  __syncthreads();
  for (int s = 128; s; s >>= 1) {
    if (tid < s) red[tid] += red[tid + s];
    __syncthreads();
  }
  float inv_denom = 1.0f / red[0];
  __syncthreads();
  int d = tid & 63, kg = tid >> 6;
  float acc = 0.f;
  for (int kk = kg; kk < nk; kk += 4)
    acc += sc[kk] * v[(((size_t)b * Ld + kk) * Hd + h) * Dd + d];
  red[tid] = acc;
  __syncthreads();
  if (kg == 0) {
    float r = red[d] + red[64 + d] + red[128 + d] + red[192 + d];
    out[(((size_t)b * Ld + t) * Hd + h) * Dd + d] = r * inv_denom;
  }
}

// ---------------------------------------------------------------------------
extern "C" void kernel_launch(void* const* d_in, const int* in_sizes, int n_in,
                              void* d_out, int out_size, void* d_ws,
                              size_t ws_size, hipStream_t stream) {
  const float* q = (const float*)d_in[0];
  const float* k = (const float*)d_in[1];
  const float* v = (const float*)d_in[2];
  const int* ridx = (const int*)d_in[4];
  float* out = (float*)d_out;

  char* ws = (char*)d_ws;
  // layout (bytes, all 16B aligned):
  float* M = (float*)(ws + 0);              // 262144
  int* topIdx = (int*)(ws + 262144);        //   5120
  float* invden = (float*)(ws + 267264);    //   5120
  float* csum = (float*)(ws + 272384);      // 1048576 (32*128*64*4)
  float* partial = (float*)(ws + 1320960);  // 2621440 (1280*8*64*4)
  float* P = (float*)(ws + 3942400);        // 10485760 (1280*2048*4)
  const size_t need_new = 3942400 + 10485760;

  compute_M_kernel<<<Bd * Hd * (Ld / 4), 256, 0, stream>>>(q, k, ridx, M);
  topk_kernel<<<Bd * Hd, 256, 0, stream>>>(M, topIdx);
  chunk_sums_kernel<<<Bd * Hd * NCHUNK, 256, 0, stream>>>(v, csum);
  scan_chunks_kernel<<<Bd * Hd, 64, 0, stream>>>(csum);
  cumsum_write_kernel<<<Bd * Hd * NCHUNK, 64, 0, stream>>>(v, csum, out);

  if (ws_size >= need_new) {
    scores_kernel<<<Bd * Hd * KS, 256, 0, stream>>>(q, k, topIdx, P);
    softmax_prep_kernel<<<Bd * Hd * NTOP, 256, 0, stream>>>(topIdx, P, invden);
    pv_partial_kernel<<<Bd * Hd * NTOP * VS, 256, 0, stream>>>(v, topIdx, P, partial);
    pv_combine_kernel<<<Bd * Hd * NTOP, 64, 0, stream>>>(partial, invden, topIdx, out);
  } else {
    attn_update_kernel<<<Bd * Hd * NTOP, 256, 0, stream>>>(q, k, v, topIdx, out);
  }
}

// Round 3
// 207.885 us; speedup vs baseline: 2.0351x; 1.5168x over previous
//
#include <hip/hip_runtime.h>

#define Bd 4
#define Hd 8
#define Ld 2048
#define Dd 64
#define Ud 40
#define NTOP 40
#define NCHUNK 128
#define CSZ 16   // Ld / NCHUNK

#define KS 16     // k-splits for scores kernel
#define KTILE 128 // Ld / KS
#define QSTR 68   // padded LDS stride (floats) for q rows
#define KSTR 68   // padded LDS stride (floats) for k rows
#define VS 8      // k-splits for PV
#define VTILE 256 // Ld / VS

// ---------------------------------------------------------------------------
// Kernel 1: M[b,h,q] = max_u(dot(q, k[ridx[q,u]])) - sum_u(dot)/L
// One wave per query. 16 lanes cooperate per sampled K row (float4 each),
// 4 rows in flight per wave instruction -> coalesced 256B segments.
// XCD-swizzled blockIdx so each XCD's L2 keeps whole (b,h) K slices.
// ---------------------------------------------------------------------------
__global__ void compute_M_kernel(const float* __restrict__ q,
                                 const float* __restrict__ k,
                                 const int* __restrict__ ridx,
                                 float* __restrict__ M) {
  const int nwg = Bd * Hd * (Ld / 4);  // 16384, %8==0 -> bijective swizzle
  int orig = blockIdx.x;
  int bid = (orig & 7) * (nwg >> 3) + (orig >> 3);

  int wave = threadIdx.x >> 6;
  int lane = threadIdx.x & 63;
  int qgroup = bid % (Ld / 4);
  int bh = bid / (Ld / 4);
  int b = bh >> 3, h = bh & 7;
  int qpos = qgroup * 4 + wave;

  int g = lane >> 4;    // sample group 0..3
  int d16 = lane & 15;  // float4 slot within row

  const float* qrow = q + (((size_t)b * Ld + qpos) * Hd + h) * Dd;
  float4 qv = reinterpret_cast<const float4*>(qrow)[d16];
  const int* rbase = ridx + qpos * Ud;
  const float* kbase = k + (((size_t)b * Ld) * Hd + h) * Dd;

  float mx = -INFINITY, sm = 0.f;
#pragma unroll
  for (int j = 0; j < Ud / 4; ++j) {
    int u = g + j * 4;          // group g handles samples g, g+4, ..., g+36
    int kidx = rbase[u];        // broadcast within 16-lane group
    float4 kv = reinterpret_cast<const float4*>(
        kbase + (size_t)kidx * Hd * Dd)[d16];
    float dot = qv.x * kv.x + qv.y * kv.y + qv.z * kv.z + qv.w * kv.w;
    dot += __shfl_xor(dot, 1);
    dot += __shfl_xor(dot, 2);
    dot += __shfl_xor(dot, 4);
    dot += __shfl_xor(dot, 8);  // all 16 lanes now hold full dot
    mx = fmaxf(mx, dot);
    sm += dot;
  }
  // combine the 4 groups (each lane holds its group's running stats)
  mx = fmaxf(mx, __shfl_xor(mx, 16));
  sm += __shfl_xor(sm, 16);
  mx = fmaxf(mx, __shfl_xor(mx, 32));
  sm += __shfl_xor(sm, 32);
  if (lane == 0) M[bh * Ld + qpos] = mx - sm * (1.0f / (float)Ld);
}

// ---------------------------------------------------------------------------
// Kernel 2: top-40 indices per (b,h) via 40 x iterative argmax in LDS.
// ---------------------------------------------------------------------------
__global__ void topk_kernel(const float* __restrict__ M,
                            int* __restrict__ topIdx) {
  __shared__ float vals[Ld];
  __shared__ float rv[256];
  __shared__ int ri[256];
  int bh = blockIdx.x;
  int tid = threadIdx.x;
  for (int i = tid; i < Ld; i += 256) vals[i] = M[bh * Ld + i];
  __syncthreads();
  for (int it = 0; it < NTOP; ++it) {
    float best = -INFINITY;
    int bidx = Ld;
    for (int i = tid; i < Ld; i += 256) {
      float v = vals[i];
      if (v > best) { best = v; bidx = i; }
    }
    rv[tid] = best;
    ri[tid] = bidx;
    __syncthreads();
    for (int s = 128; s; s >>= 1) {
      if (tid < s) {
        float v2 = rv[tid + s];
        int i2 = ri[tid + s];
        if (v2 > rv[tid] || (v2 == rv[tid] && i2 < ri[tid])) {
          rv[tid] = v2;
          ri[tid] = i2;
        }
      }
      __syncthreads();
    }
    if (tid == 0) {
      topIdx[bh * NTOP + it] = ri[0];
      vals[ri[0]] = -INFINITY;
    }
    __syncthreads();
  }
}

// ---------------------------------------------------------------------------
// Kernel 3a: per-chunk sums of V along L. Block (256 thr) per (b,h,chunk).
// ---------------------------------------------------------------------------
__global__ void chunk_sums_kernel(const float* __restrict__ v,
                                  float* __restrict__ csum) {
  __shared__ float red[256];
  int blk = blockIdx.x;  // bh*NCHUNK + c
  int c = blk % NCHUNK, bh = blk / NCHUNK;
  int b = bh >> 3, h = bh & 7;
  int d = threadIdx.x & 63, jg = threadIdx.x >> 6;
  int t0 = c * CSZ;
  float s = 0.f;
#pragma unroll
  for (int j = jg; j < CSZ; j += 4)
    s += v[(((size_t)b * Ld + t0 + j) * Hd + h) * Dd + d];
  red[threadIdx.x] = s;
  __syncthreads();
  if (jg == 0)
    csum[(size_t)blk * Dd + d] = red[d] + red[64 + d] + red[128 + d] + red[192 + d];
}

// ---------------------------------------------------------------------------
// Kernel 3b: exclusive scan of the NCHUNK chunk sums per (b,h,d).
// ---------------------------------------------------------------------------
__global__ void scan_chunks_kernel(float* __restrict__ csum) {
  int bh = blockIdx.x;
  int d = threadIdx.x;
  float acc = 0.f;
#pragma unroll 8
  for (int c = 0; c < NCHUNK; ++c) {
    size_t i = ((size_t)bh * NCHUNK + c) * Dd + d;
    float s = csum[i];
    csum[i] = acc;
    acc += s;
  }
}

// ---------------------------------------------------------------------------
// Kernel 3c: inclusive cumsum write.
// ---------------------------------------------------------------------------
__global__ void cumsum_write_kernel(const float* __restrict__ v,
                                    const float* __restrict__ csum,
                                    float* __restrict__ out) {
  int blk = blockIdx.x;
  int c = blk % NCHUNK, bh = blk / NCHUNK;
  int b = bh >> 3, h = bh & 7;
  int d = threadIdx.x;
  float acc = csum[(size_t)blk * Dd + d];
  int t0 = c * CSZ;
#pragma unroll 4
  for (int j = 0; j < CSZ; ++j) {
    size_t idx = (((size_t)b * Ld + t0 + j) * Hd + h) * Dd + d;
    acc += v[idx];
    out[idx] = acc;
  }
}

// ---------------------------------------------------------------------------
// Kernel 4a: masked scaled scores for all 40 selected queries x K tile.
// Grid: bh(32) x KS(16). LDS-staged panel GEMM, 5u x 4k register tile.
// ---------------------------------------------------------------------------
__global__ __launch_bounds__(256) void scores_kernel(
    const float* __restrict__ q, const float* __restrict__ k,
    const int* __restrict__ topIdx, float* __restrict__ P) {
  __shared__ float qs[NTOP * QSTR];
  __shared__ float ks[KTILE * KSTR];
  __shared__ int ts[NTOP];
  int tid = threadIdx.x;
  int ksplit = blockIdx.x % KS;
  int bh = blockIdx.x / KS;
  int b = bh >> 3, h = bh & 7;
  int k0 = ksplit * KTILE;

  if (tid < NTOP) ts[tid] = topIdx[bh * NTOP + tid];
  __syncthreads();

  for (int i = tid; i < NTOP * 16; i += 256) {
    int u = i >> 4, p = i & 15;
    float4 qv = reinterpret_cast<const float4*>(
        q + (((size_t)b * Ld + ts[u]) * Hd + h) * Dd)[p];
    *reinterpret_cast<float4*>(&qs[u * QSTR + p * 4]) = qv;
  }
  for (int i = tid; i < KTILE * 16; i += 256) {
    int r = i >> 4, p = i & 15;
    float4 kv = reinterpret_cast<const float4*>(
        k + (((size_t)b * Ld + k0 + r) * Hd + h) * Dd)[p];
    *reinterpret_cast<float4*>(&ks[r * KSTR + p * 4]) = kv;
  }
  __syncthreads();

  int ug = tid & 7, kg = tid >> 3;
  int ub = ug * 5, kb = kg * 4;
  float acc[5][4] = {};
  for (int dd = 0; dd < Dd; dd += 4) {
    float4 kv[4], qv[5];
#pragma unroll
    for (int i = 0; i < 4; ++i)
      kv[i] = *reinterpret_cast<const float4*>(&ks[(kb + i) * KSTR + dd]);
#pragma unroll
    for (int i = 0; i < 5; ++i)
      qv[i] = *reinterpret_cast<const float4*>(&qs[(ub + i) * QSTR + dd]);
#pragma unroll
    for (int ui = 0; ui < 5; ++ui)
#pragma unroll
      for (int ki = 0; ki < 4; ++ki)
        acc[ui][ki] += qv[ui].x * kv[ki].x + qv[ui].y * kv[ki].y +
                       qv[ui].z * kv[ki].z + qv[ui].w * kv[ki].w;
  }

#pragma unroll
  for (int ui = 0; ui < 5; ++ui) {
    int u = ub + ui;
    int t = ts[u];
    float4 o;
    o.x = (k0 + kb + 0 <= t) ? acc[ui][0] * 0.125f : -INFINITY;
    o.y = (k0 + kb + 1 <= t) ? acc[ui][1] * 0.125f : -INFINITY;
    o.z = (k0 + kb + 2 <= t) ? acc[ui][2] * 0.125f : -INFINITY;
    o.w = (k0 + kb + 3 <= t) ? acc[ui][3] * 0.125f : -INFINITY;
    *reinterpret_cast<float4*>(&P[((size_t)bh * NTOP + u) * Ld + k0 + kb]) = o;
  }
}

// ---------------------------------------------------------------------------
// Kernel 4b: per selected row: max, exp in place, 1/denominator.
// ---------------------------------------------------------------------------
__global__ void softmax_prep_kernel(const int* __restrict__ topIdx,
                                    float* __restrict__ P,
                                    float* __restrict__ invden) {
  __shared__ float red[256];
  int row = blockIdx.x;
  int t = topIdx[row];
  int nk = t + 1;
  float* pr = P + (size_t)row * Ld;
  int tid = threadIdx.x;
  float lmax = -INFINITY;
  for (int i = tid; i < nk; i += 256) lmax = fmaxf(lmax, pr[i]);
  red[tid] = lmax;
  __syncthreads();
  for (int s = 128; s; s >>= 1) {
    if (tid < s) red[tid] = fmaxf(red[tid], red[tid + s]);
    __syncthreads();
  }
  float m = red[0];
  __syncthreads();
  float lsum = 0.f;
  for (int i = tid; i < nk; i += 256) {
    float p = __expf(pr[i] - m);
    pr[i] = p;
    lsum += p;
  }
  red[tid] = lsum;
  __syncthreads();
  for (int s = 128; s; s >>= 1) {
    if (tid < s) red[tid] += red[tid + s];
    __syncthreads();
  }
  if (tid == 0) invden[row] = 1.0f / red[0];
}

// ---------------------------------------------------------------------------
// Kernel 4c: split-K partial PV.
// ---------------------------------------------------------------------------
__global__ void pv_partial_kernel(const float* __restrict__ v,
                                  const int* __restrict__ topIdx,
                                  const float* __restrict__ P,
                                  float* __restrict__ partial) {
  __shared__ float red[256];
  int vs = blockIdx.x % VS;
  int row = blockIdx.x / VS;
  int bh = row / NTOP;
  int b = bh >> 3, h = bh & 7;
  int t = topIdx[row];
  int d = threadIdx.x & 63, kg = threadIdx.x >> 6;
  int k0 = vs * VTILE;
  float acc = 0.f;
  if (k0 <= t) {
    int kend = min(t, k0 + VTILE - 1);
    const float* pr = P + (size_t)row * Ld;
    for (int kk = k0 + kg; kk <= kend; kk += 4)
      acc += pr[kk] * v[(((size_t)b * Ld + kk) * Hd + h) * Dd + d];
  }
  red[threadIdx.x] = acc;
  __syncthreads();
  if (kg == 0)
    partial[(size_t)blockIdx.x * Dd + d] =
        red[d] + red[64 + d] + red[128 + d] + red[192 + d];
}

// ---------------------------------------------------------------------------
// Kernel 4d: combine partials, normalize, scatter-overwrite output rows.
// ---------------------------------------------------------------------------
__global__ void pv_combine_kernel(const float* __restrict__ partial,
                                  const float* __restrict__ invden,
                                  const int* __restrict__ topIdx,
                                  float* __restrict__ out) {
  int row = blockIdx.x;
  int d = threadIdx.x;  // 64
  int bh = row / NTOP;
  int b = bh >> 3, h = bh & 7;
  int t = topIdx[row];
  float s = 0.f;
#pragma unroll
  for (int vs = 0; vs < VS; ++vs) s += partial[((size_t)row * VS + vs) * Dd + d];
  out[(((size_t)b * Ld + t) * Hd + h) * Dd + d] = s * invden[row];
}

// ---------------------------------------------------------------------------
// Fallback attention kernel if ws is too small.
// ---------------------------------------------------------------------------
__global__ void attn_update_kernel(const float* __restrict__ q,
                                   const float* __restrict__ k,
                                   const float* __restrict__ v,
                                   const int* __restrict__ topIdx,
                                   float* __restrict__ out) {
  __shared__ float sc[Ld];
  __shared__ float qs[Dd];
  __shared__ float red[256];
  int tid = threadIdx.x;
  int bh = blockIdx.x / NTOP;
  int b = bh >> 3, h = bh & 7;
  int t = topIdx[blockIdx.x];

  if (tid < Dd) qs[tid] = q[(((size_t)b * Ld + t) * Hd + h) * Dd + tid];
  __syncthreads();

  int nk = t + 1;
  const float4* qv4 = reinterpret_cast<const float4*>(qs);
  float lmax = -INFINITY;
  for (int kk = tid; kk < nk; kk += 256) {
    const float4* kr = reinterpret_cast<const float4*>(
        k + (((size_t)b * Ld + kk) * Hd + h) * Dd);
    float dot = 0.f;
#pragma unroll
    for (int j = 0; j < Dd / 4; ++j) {
      float4 a = qv4[j];
      float4 bb = kr[j];
      dot += a.x * bb.x + a.y * bb.y + a.z * bb.z + a.w * bb.w;
    }
    dot *= 0.125f;
    sc[kk] = dot;
    lmax = fmaxf(lmax, dot);
  }
  red[tid] = lmax;
  __syncthreads();
  for (int s = 128; s; s >>= 1) {
    if (tid < s) red[tid] = fmaxf(red[tid], red[tid + s]);
    __syncthreads();
  }
  float m = red[0];
  __syncthreads();
  float lsum = 0.f;
  for (int kk = tid; kk < nk; kk += 256) {
    float p = __expf(sc[kk] - m);
    sc[kk] = p;
    lsum += p;
  }
  red[tid] = lsum;
  __syncthreads();
  for (int s = 128; s; s >>= 1) {
    if (tid < s) red[tid] += red[tid + s];
    __syncthreads();
  }
  float inv_denom = 1.0f / red[0];
  __syncthreads();
  int d = tid & 63, kg = tid >> 6;
  float acc = 0.f;
  for (int kk = kg; kk < nk; kk += 4)
    acc += sc[kk] * v[(((size_t)b * Ld + kk) * Hd + h) * Dd + d];
  red[tid] = acc;
  __syncthreads();
  if (kg == 0) {
    float r = red[d] + red[64 + d] + red[128 + d] + red[192 + d];
    out[(((size_t)b * Ld + t) * Hd + h) * Dd + d] = r * inv_denom;
  }
}

// ---------------------------------------------------------------------------
extern "C" void kernel_launch(void* const* d_in, const int* in_sizes, int n_in,
                              void* d_out, int out_size, void* d_ws,
                              size_t ws_size, hipStream_t stream) {
  const float* q = (const float*)d_in[0];
  const float* k = (const float*)d_in[1];
  const float* v = (const float*)d_in[2];
  const int* ridx = (const int*)d_in[4];
  float* out = (float*)d_out;

  char* ws = (char*)d_ws;
  float* M = (float*)(ws + 0);              // 262144
  int* topIdx = (int*)(ws + 262144);        //   5120
  float* invden = (float*)(ws + 267264);    //   5120
  float* csum = (float*)(ws + 272384);      // 1048576
  float* partial = (float*)(ws + 1320960);  // 2621440
  float* P = (float*)(ws + 3942400);        // 10485760
  const size_t need_new = 3942400 + 10485760;

  compute_M_kernel<<<Bd * Hd * (Ld / 4), 256, 0, stream>>>(q, k, ridx, M);
  topk_kernel<<<Bd * Hd, 256, 0, stream>>>(M, topIdx);
  chunk_sums_kernel<<<Bd * Hd * NCHUNK, 256, 0, stream>>>(v, csum);
  scan_chunks_kernel<<<Bd * Hd, 64, 0, stream>>>(csum);
  cumsum_write_kernel<<<Bd * Hd * NCHUNK, 64, 0, stream>>>(v, csum, out);

  if (ws_size >= need_new) {
    scores_kernel<<<Bd * Hd * KS, 256, 0, stream>>>(q, k, topIdx, P);
    softmax_prep_kernel<<<Bd * Hd * NTOP, 256, 0, stream>>>(topIdx, P, invden);
    pv_partial_kernel<<<Bd * Hd * NTOP * VS, 256, 0, stream>>>(v, topIdx, P, partial);
    pv_combine_kernel<<<Bd * Hd * NTOP, 64, 0, stream>>>(partial, invden, topIdx, out);
  } else {
    attn_update_kernel<<<Bd * Hd * NTOP, 256, 0, stream>>>(q, k, v, topIdx, out);
  }
}

// Round 4
// 155.585 us; speedup vs baseline: 2.7192x; 1.3362x over previous
//
#include <hip/hip_runtime.h>

#define Bd 4
#define Hd 8
#define Ld 2048
#define Dd 64
#define Ud 40
#define NTOP 40
#define NCHUNK 128
#define CSZ 16   // Ld / NCHUNK

#define KS 16     // k-splits for scores kernel
#define KTILE 128 // Ld / KS
#define QSTR 68   // padded LDS stride (floats) for q rows
#define KSTR 68   // padded LDS stride (floats) for k rows
#define VS 8      // k-splits for PV
#define VTILE 256 // Ld / VS

// ---------------------------------------------------------------------------
// Kernel 1: M[b,h,q] = max_u(dot(q, k[ridx[q,u]])) - sum_u(dot)/L
// 16 lanes cooperate per sampled K row; XCD-swizzled blockIdx.
// ---------------------------------------------------------------------------
__global__ void compute_M_kernel(const float* __restrict__ q,
                                 const float* __restrict__ k,
                                 const int* __restrict__ ridx,
                                 float* __restrict__ M) {
  const int nwg = Bd * Hd * (Ld / 4);  // 16384, %8==0 -> bijective swizzle
  int orig = blockIdx.x;
  int bid = (orig & 7) * (nwg >> 3) + (orig >> 3);

  int wave = threadIdx.x >> 6;
  int lane = threadIdx.x & 63;
  int qgroup = bid % (Ld / 4);
  int bh = bid / (Ld / 4);
  int b = bh >> 3, h = bh & 7;
  int qpos = qgroup * 4 + wave;

  int g = lane >> 4;    // sample group 0..3
  int d16 = lane & 15;  // float4 slot within row

  const float* qrow = q + (((size_t)b * Ld + qpos) * Hd + h) * Dd;
  float4 qv = reinterpret_cast<const float4*>(qrow)[d16];
  const int* rbase = ridx + qpos * Ud;
  const float* kbase = k + (((size_t)b * Ld) * Hd + h) * Dd;

  float mx = -INFINITY, sm = 0.f;
#pragma unroll
  for (int j = 0; j < Ud / 4; ++j) {
    int u = g + j * 4;
    int kidx = rbase[u];
    float4 kv = reinterpret_cast<const float4*>(
        kbase + (size_t)kidx * Hd * Dd)[d16];
    float dot = qv.x * kv.x + qv.y * kv.y + qv.z * kv.z + qv.w * kv.w;
    dot += __shfl_xor(dot, 1);
    dot += __shfl_xor(dot, 2);
    dot += __shfl_xor(dot, 4);
    dot += __shfl_xor(dot, 8);
    mx = fmaxf(mx, dot);
    sm += dot;
  }
  mx = fmaxf(mx, __shfl_xor(mx, 16));
  sm += __shfl_xor(sm, 16);
  mx = fmaxf(mx, __shfl_xor(mx, 32));
  sm += __shfl_xor(sm, 32);
  if (lane == 0) M[bh * Ld + qpos] = mx - sm * (1.0f / (float)Ld);
}

// ---------------------------------------------------------------------------
// Kernel 2: top-40 indices per (b,h) via 40 x iterative argmax in LDS.
// ---------------------------------------------------------------------------
__global__ void topk_kernel(const float* __restrict__ M,
                            int* __restrict__ topIdx) {
  __shared__ float vals[Ld];
  __shared__ float rv[256];
  __shared__ int ri[256];
  int bh = blockIdx.x;
  int tid = threadIdx.x;
  for (int i = tid; i < Ld; i += 256) vals[i] = M[bh * Ld + i];
  __syncthreads();
  for (int it = 0; it < NTOP; ++it) {
    float best = -INFINITY;
    int bidx = Ld;
    for (int i = tid; i < Ld; i += 256) {
      float v = vals[i];
      if (v > best) { best = v; bidx = i; }
    }
    rv[tid] = best;
    ri[tid] = bidx;
    __syncthreads();
    for (int s = 128; s; s >>= 1) {
      if (tid < s) {
        float v2 = rv[tid + s];
        int i2 = ri[tid + s];
        if (v2 > rv[tid] || (v2 == rv[tid] && i2 < ri[tid])) {
          rv[tid] = v2;
          ri[tid] = i2;
        }
      }
      __syncthreads();
    }
    if (tid == 0) {
      topIdx[bh * NTOP + it] = ri[0];
      vals[ri[0]] = -INFINITY;
    }
    __syncthreads();
  }
}

// ---------------------------------------------------------------------------
// Kernel 3a: per-chunk sums of V along L. Block (256 thr) per (b,h,chunk).
// ---------------------------------------------------------------------------
__global__ void chunk_sums_kernel(const float* __restrict__ v,
                                  float* __restrict__ csum) {
  __shared__ float red[256];
  int blk = blockIdx.x;
  int c = blk % NCHUNK, bh = blk / NCHUNK;
  int b = bh >> 3, h = bh & 7;
  int d = threadIdx.x & 63, jg = threadIdx.x >> 6;
  int t0 = c * CSZ;
  float s = 0.f;
#pragma unroll
  for (int j = jg; j < CSZ; j += 4)
    s += v[(((size_t)b * Ld + t0 + j) * Hd + h) * Dd + d];
  red[threadIdx.x] = s;
  __syncthreads();
  if (jg == 0)
    csum[(size_t)blk * Dd + d] = red[d] + red[64 + d] + red[128 + d] + red[192 + d];
}

// ---------------------------------------------------------------------------
// Kernel 3b: exclusive scan of the NCHUNK chunk sums per (b,h,d).
// ---------------------------------------------------------------------------
__global__ void scan_chunks_kernel(float* __restrict__ csum) {
  int bh = blockIdx.x;
  int d = threadIdx.x;
  float acc = 0.f;
#pragma unroll 8
  for (int c = 0; c < NCHUNK; ++c) {
    size_t i = ((size_t)bh * NCHUNK + c) * Dd + d;
    float s = csum[i];
    csum[i] = acc;
    acc += s;
  }
}

// ---------------------------------------------------------------------------
// Kernel 3c: inclusive cumsum write.
// ---------------------------------------------------------------------------
__global__ void cumsum_write_kernel(const float* __restrict__ v,
                                    const float* __restrict__ csum,
                                    float* __restrict__ out) {
  int blk = blockIdx.x;
  int c = blk % NCHUNK, bh = blk / NCHUNK;
  int b = bh >> 3, h = bh & 7;
  int d = threadIdx.x;
  float acc = csum[(size_t)blk * Dd + d];
  int t0 = c * CSZ;
#pragma unroll 4
  for (int j = 0; j < CSZ; ++j) {
    size_t idx = (((size_t)b * Ld + t0 + j) * Hd + h) * Dd + d;
    acc += v[idx];
    out[idx] = acc;
  }
}

// ---------------------------------------------------------------------------
// Kernel 4a: masked scaled scores for all 40 selected queries x K tile.
// ---------------------------------------------------------------------------
__global__ __launch_bounds__(256) void scores_kernel(
    const float* __restrict__ q, const float* __restrict__ k,
    const int* __restrict__ topIdx, float* __restrict__ P) {
  __shared__ float qs[NTOP * QSTR];
  __shared__ float ks[KTILE * KSTR];
  __shared__ int ts[NTOP];
  int tid = threadIdx.x;
  int ksplit = blockIdx.x % KS;
  int bh = blockIdx.x / KS;
  int b = bh >> 3, h = bh & 7;
  int k0 = ksplit * KTILE;

  if (tid < NTOP) ts[tid] = topIdx[bh * NTOP + tid];
  __syncthreads();

  for (int i = tid; i < NTOP * 16; i += 256) {
    int u = i >> 4, p = i & 15;
    float4 qv = reinterpret_cast<const float4*>(
        q + (((size_t)b * Ld + ts[u]) * Hd + h) * Dd)[p];
    *reinterpret_cast<float4*>(&qs[u * QSTR + p * 4]) = qv;
  }
  for (int i = tid; i < KTILE * 16; i += 256) {
    int r = i >> 4, p = i & 15;
    float4 kv = reinterpret_cast<const float4*>(
        k + (((size_t)b * Ld + k0 + r) * Hd + h) * Dd)[p];
    *reinterpret_cast<float4*>(&ks[r * KSTR + p * 4]) = kv;
  }
  __syncthreads();

  int ug = tid & 7, kg = tid >> 3;
  int ub = ug * 5, kb = kg * 4;
  float acc[5][4] = {};
  for (int dd = 0; dd < Dd; dd += 4) {
    float4 kv[4], qv[5];
#pragma unroll
    for (int i = 0; i < 4; ++i)
      kv[i] = *reinterpret_cast<const float4*>(&ks[(kb + i) * KSTR + dd]);
#pragma unroll
    for (int i = 0; i < 5; ++i)
      qv[i] = *reinterpret_cast<const float4*>(&qs[(ub + i) * QSTR + dd]);
#pragma unroll
    for (int ui = 0; ui < 5; ++ui)
#pragma unroll
      for (int ki = 0; ki < 4; ++ki)
        acc[ui][ki] += qv[ui].x * kv[ki].x + qv[ui].y * kv[ki].y +
                       qv[ui].z * kv[ki].z + qv[ui].w * kv[ki].w;
  }

#pragma unroll
  for (int ui = 0; ui < 5; ++ui) {
    int u = ub + ui;
    int t = ts[u];
    float4 o;
    o.x = (k0 + kb + 0 <= t) ? acc[ui][0] * 0.125f : -INFINITY;
    o.y = (k0 + kb + 1 <= t) ? acc[ui][1] * 0.125f : -INFINITY;
    o.z = (k0 + kb + 2 <= t) ? acc[ui][2] * 0.125f : -INFINITY;
    o.w = (k0 + kb + 3 <= t) ? acc[ui][3] * 0.125f : -INFINITY;
    *reinterpret_cast<float4*>(&P[((size_t)bh * NTOP + u) * Ld + k0 + kb]) = o;
  }
}

// ---------------------------------------------------------------------------
// Kernel 4b: per selected row: max, exp in place, 1/denominator.
// ---------------------------------------------------------------------------
__global__ void softmax_prep_kernel(const int* __restrict__ topIdx,
                                    float* __restrict__ P,
                                    float* __restrict__ invden) {
  __shared__ float red[256];
  int row = blockIdx.x;
  int t = topIdx[row];
  int nk = t + 1;
  float* pr = P + (size_t)row * Ld;
  int tid = threadIdx.x;
  float lmax = -INFINITY;
  for (int i = tid; i < nk; i += 256) lmax = fmaxf(lmax, pr[i]);
  red[tid] = lmax;
  __syncthreads();
  for (int s = 128; s; s >>= 1) {
    if (tid < s) red[tid] = fmaxf(red[tid], red[tid + s]);
    __syncthreads();
  }
  float m = red[0];
  __syncthreads();
  float lsum = 0.f;
  for (int i = tid; i < nk; i += 256) {
    float p = __expf(pr[i] - m);
    pr[i] = p;
    lsum += p;
  }
  red[tid] = lsum;
  __syncthreads();
  for (int s = 128; s; s >>= 1) {
    if (tid < s) red[tid] += red[tid + s];
    __syncthreads();
  }
  if (tid == 0) invden[row] = 1.0f / red[0];
}

// ---------------------------------------------------------------------------
// Kernel 4c: split-K partial PV, float4-vectorized.
// Lane = (kg = lane>>4, d16 = lane&15). Each 16-lane group owns one k row
// per iteration and loads a float4 slice -> 4 coalesced 256B segments per
// wave-instruction, unrolled for ILP. Wave w covers k in [k0+64w, k0+64w+63].
// ---------------------------------------------------------------------------
__global__ __launch_bounds__(256) void pv_partial_kernel(
    const float* __restrict__ v, const int* __restrict__ topIdx,
    const float* __restrict__ P, float* __restrict__ partial) {
  __shared__ float4 red4[64];  // 4 waves x 16 slots
  int vs = blockIdx.x % VS;
  int row = blockIdx.x / VS;
  int bh = row / NTOP;
  int b = bh >> 3, h = bh & 7;
  int t = topIdx[row];
  int lane = threadIdx.x & 63, wave = threadIdx.x >> 6;
  int d16 = lane & 15, kg = lane >> 4;
  int base = vs * VTILE + wave * 64;

  float4 acc = {0.f, 0.f, 0.f, 0.f};
  if (base <= t) {
    const float* pr = P + (size_t)row * Ld;
    const float* vb = v + ((size_t)b * Ld * Hd + h) * Dd;
#pragma unroll 4
    for (int it = 0; it < 16; ++it) {
      int kk = base + it * 4 + kg;
      if (kk <= t) {
        float p = pr[kk];
        float4 vv =
            reinterpret_cast<const float4*>(vb + (size_t)kk * Hd * Dd)[d16];
        acc.x += p * vv.x;
        acc.y += p * vv.y;
        acc.z += p * vv.z;
        acc.w += p * vv.w;
      }
    }
  }
  // reduce over the 4 k-groups within the wave
  acc.x += __shfl_xor(acc.x, 16);
  acc.y += __shfl_xor(acc.y, 16);
  acc.z += __shfl_xor(acc.z, 16);
  acc.w += __shfl_xor(acc.w, 16);
  acc.x += __shfl_xor(acc.x, 32);
  acc.y += __shfl_xor(acc.y, 32);
  acc.z += __shfl_xor(acc.z, 32);
  acc.w += __shfl_xor(acc.w, 32);
  if (lane < 16) red4[wave * 16 + lane] = acc;
  __syncthreads();
  int tid = threadIdx.x;
  if (tid < 16) {
    float4 a = red4[tid], bb = red4[16 + tid], c = red4[32 + tid],
           dd4 = red4[48 + tid];
    float4 r;
    r.x = a.x + bb.x + c.x + dd4.x;
    r.y = a.y + bb.y + c.y + dd4.y;
    r.z = a.z + bb.z + c.z + dd4.z;
    r.w = a.w + bb.w + c.w + dd4.w;
    reinterpret_cast<float4*>(partial + (size_t)blockIdx.x * Dd)[tid] = r;
  }
}

// ---------------------------------------------------------------------------
// Kernel 4d: combine partials, normalize, scatter-overwrite output rows.
// ---------------------------------------------------------------------------
__global__ void pv_combine_kernel(const float* __restrict__ partial,
                                  const float* __restrict__ invden,
                                  const int* __restrict__ topIdx,
                                  float* __restrict__ out) {
  int row = blockIdx.x;
  int d = threadIdx.x;  // 64
  int bh = row / NTOP;
  int b = bh >> 3, h = bh & 7;
  int t = topIdx[row];
  float s = 0.f;
#pragma unroll
  for (int vs = 0; vs < VS; ++vs) s += partial[((size_t)row * VS + vs) * Dd + d];
  out[(((size_t)b * Ld + t) * Hd + h) * Dd + d] = s * invden[row];
}

// ---------------------------------------------------------------------------
// Fallback attention kernel if ws is too small.
// ---------------------------------------------------------------------------
__global__ void attn_update_kernel(const float* __restrict__ q,
                                   const float* __restrict__ k,
                                   const float* __restrict__ v,
                                   const int* __restrict__ topIdx,
                                   float* __restrict__ out) {
  __shared__ float sc[Ld];
  __shared__ float qs[Dd];
  __shared__ float red[256];
  int tid = threadIdx.x;
  int bh = blockIdx.x / NTOP;
  int b = bh >> 3, h = bh & 7;
  int t = topIdx[blockIdx.x];

  if (tid < Dd) qs[tid] = q[(((size_t)b * Ld + t) * Hd + h) * Dd + tid];
  __syncthreads();

  int nk = t + 1;
  const float4* qv4 = reinterpret_cast<const float4*>(qs);
  float lmax = -INFINITY;
  for (int kk = tid; kk < nk; kk += 256) {
    const float4* kr = reinterpret_cast<const float4*>(
        k + (((size_t)b * Ld + kk) * Hd + h) * Dd);
    float dot = 0.f;
#pragma unroll
    for (int j = 0; j < Dd / 4; ++j) {
      float4 a = qv4[j];
      float4 bb = kr[j];
      dot += a.x * bb.x + a.y * bb.y + a.z * bb.z + a.w * bb.w;
    }
    dot *= 0.125f;
    sc[kk] = dot;
    lmax = fmaxf(lmax, dot);
  }
  red[tid] = lmax;
  __syncthreads();
  for (int s = 128; s; s >>= 1) {
    if (tid < s) red[tid] = fmaxf(red[tid], red[tid + s]);
    __syncthreads();
  }
  float m = red[0];
  __syncthreads();
  float lsum = 0.f;
  for (int kk = tid; kk < nk; kk += 256) {
    float p = __expf(sc[kk] - m);
    sc[kk] = p;
    lsum += p;
  }
  red[tid] = lsum;
  __syncthreads();
  for (int s = 128; s; s >>= 1) {
    if (tid < s) red[tid] += red[tid + s];
    __syncthreads();
  }
  float inv_denom = 1.0f / red[0];
  __syncthreads();
  int d = tid & 63, kg = tid >> 6;
  float acc = 0.f;
  for (int kk = kg; kk < nk; kk += 4)
    acc += sc[kk] * v[(((size_t)b * Ld + kk) * Hd + h) * Dd + d];
  red[tid] = acc;
  __syncthreads();
  if (kg == 0) {
    float r = red[d] + red[64 + d] + red[128 + d] + red[192 + d];
    out[(((size_t)b * Ld + t) * Hd + h) * Dd + d] = r * inv_denom;
  }
}

// ---------------------------------------------------------------------------
extern "C" void kernel_launch(void* const* d_in, const int* in_sizes, int n_in,
                              void* d_out, int out_size, void* d_ws,
                              size_t ws_size, hipStream_t stream) {
  const float* q = (const float*)d_in[0];
  const float* k = (const float*)d_in[1];
  const float* v = (const float*)d_in[2];
  const int* ridx = (const int*)d_in[4];
  float* out = (float*)d_out;

  char* ws = (char*)d_ws;
  float* M = (float*)(ws + 0);              // 262144
  int* topIdx = (int*)(ws + 262144);        //   5120
  float* invden = (float*)(ws + 267264);    //   5120
  float* csum = (float*)(ws + 272384);      // 1048576
  float* partial = (float*)(ws + 1320960);  // 2621440
  float* P = (float*)(ws + 3942400);        // 10485760
  const size_t need_new = 3942400 + 10485760;

  compute_M_kernel<<<Bd * Hd * (Ld / 4), 256, 0, stream>>>(q, k, ridx, M);
  topk_kernel<<<Bd * Hd, 256, 0, stream>>>(M, topIdx);
  chunk_sums_kernel<<<Bd * Hd * NCHUNK, 256, 0, stream>>>(v, csum);
  scan_chunks_kernel<<<Bd * Hd, 64, 0, stream>>>(csum);
  cumsum_write_kernel<<<Bd * Hd * NCHUNK, 64, 0, stream>>>(v, csum, out);

  if (ws_size >= need_new) {
    scores_kernel<<<Bd * Hd * KS, 256, 0, stream>>>(q, k, topIdx, P);
    softmax_prep_kernel<<<Bd * Hd * NTOP, 256, 0, stream>>>(topIdx, P, invden);
    pv_partial_kernel<<<Bd * Hd * NTOP * VS, 256, 0, stream>>>(v, topIdx, P, partial);
    pv_combine_kernel<<<Bd * Hd * NTOP, 64, 0, stream>>>(partial, invden, topIdx, out);
  } else {
    attn_update_kernel<<<Bd * Hd * NTOP, 256, 0, stream>>>(q, k, v, topIdx, out);
  }
}

// Round 5
// 145.040 us; speedup vs baseline: 2.9169x; 1.0727x over previous
//
#include <hip/hip_runtime.h>

#define Bd 4
#define Hd 8
#define Ld 2048
#define Dd 64
#define Ud 40
#define NTOP 40
#define NCHUNK 128
#define CSZ 16   // Ld / NCHUNK

#define KS 16     // k-splits for scores kernel
#define KTILE 128 // Ld / KS
#define QSTR 68   // padded LDS stride (floats) for q rows
#define KSTR 68   // padded LDS stride (floats) for k rows
#define VS 8      // k-splits for PV
#define VTILE 256 // Ld / VS

// ---------------------------------------------------------------------------
// Kernel 1: M[b,h,q] = max_u(dot(q, k[ridx[q,u]])) - sum_u(dot)/L
// 16 lanes cooperate per sampled K row; XCD-swizzled blockIdx.
// ---------------------------------------------------------------------------
__global__ void compute_M_kernel(const float* __restrict__ q,
                                 const float* __restrict__ k,
                                 const int* __restrict__ ridx,
                                 float* __restrict__ M) {
  const int nwg = Bd * Hd * (Ld / 4);  // 16384, %8==0 -> bijective swizzle
  int orig = blockIdx.x;
  int bid = (orig & 7) * (nwg >> 3) + (orig >> 3);

  int wave = threadIdx.x >> 6;
  int lane = threadIdx.x & 63;
  int qgroup = bid % (Ld / 4);
  int bh = bid / (Ld / 4);
  int b = bh >> 3, h = bh & 7;
  int qpos = qgroup * 4 + wave;

  int g = lane >> 4;    // sample group 0..3
  int d16 = lane & 15;  // float4 slot within row

  const float* qrow = q + (((size_t)b * Ld + qpos) * Hd + h) * Dd;
  float4 qv = reinterpret_cast<const float4*>(qrow)[d16];
  const int* rbase = ridx + qpos * Ud;
  const float* kbase = k + (((size_t)b * Ld) * Hd + h) * Dd;

  float mx = -INFINITY, sm = 0.f;
#pragma unroll
  for (int j = 0; j < Ud / 4; ++j) {
    int u = g + j * 4;
    int kidx = rbase[u];
    float4 kv = reinterpret_cast<const float4*>(
        kbase + (size_t)kidx * Hd * Dd)[d16];
    float dot = qv.x * kv.x + qv.y * kv.y + qv.z * kv.z + qv.w * kv.w;
    dot += __shfl_xor(dot, 1);
    dot += __shfl_xor(dot, 2);
    dot += __shfl_xor(dot, 4);
    dot += __shfl_xor(dot, 8);
    mx = fmaxf(mx, dot);
    sm += dot;
  }
  mx = fmaxf(mx, __shfl_xor(mx, 16));
  sm += __shfl_xor(sm, 16);
  mx = fmaxf(mx, __shfl_xor(mx, 32));
  sm += __shfl_xor(sm, 32);
  if (lane == 0) M[bh * Ld + qpos] = mx - sm * (1.0f / (float)Ld);
}

// ---------------------------------------------------------------------------
// Kernel 2: top-40 per (b,h). One wave; 2048 values as monotone u32 keys in
// registers (32/lane); 40 x {fused eliminate+local argmax, butterfly argmax}.
// Tie-break: lower index wins (matches jax.lax.top_k stability).
// ---------------------------------------------------------------------------
__global__ __launch_bounds__(64) void topk_kernel(const float* __restrict__ M,
                                                  int* __restrict__ topIdx) {
  int bh = blockIdx.x;
  int lane = threadIdx.x;  // 0..63
  const float* mrow = M + (size_t)bh * Ld;

  unsigned int key[32];
#pragma unroll
  for (int j = 0; j < 32; ++j) {
    unsigned int bits = __float_as_uint(mrow[lane + j * 64]);
    key[j] = (bits & 0x80000000u) ? ~bits : (bits | 0x80000000u);
  }

  int widx = -1;  // previous winner (none yet)
  for (int it = 0; it < NTOP; ++it) {
    unsigned int bk = 0u;
    int bidx = Ld + lane;  // sentinel (never selected: key 0 < any real key)
#pragma unroll
    for (int j = 0; j < 32; ++j) {
      int idx = lane + j * 64;
      unsigned int kj = (idx == widx) ? 0u : key[j];
      key[j] = kj;
      if (kj > bk) { bk = kj; bidx = idx; }  // ascending j -> lowest idx kept
    }
#pragma unroll
    for (int off = 1; off < 64; off <<= 1) {
      unsigned int ok = __shfl_xor(bk, off);
      int oi = __shfl_xor(bidx, off);
      if (ok > bk || (ok == bk && oi < bidx)) { bk = ok; bidx = oi; }
    }
    if (lane == 0) topIdx[bh * NTOP + it] = bidx;
    widx = bidx;
  }
}

// ---------------------------------------------------------------------------
// Kernel 3a: per-chunk sums of V along L. Block (256 thr) per (b,h,chunk).
// ---------------------------------------------------------------------------
__global__ void chunk_sums_kernel(const float* __restrict__ v,
                                  float* __restrict__ csum) {
  __shared__ float red[256];
  int blk = blockIdx.x;
  int c = blk % NCHUNK, bh = blk / NCHUNK;
  int b = bh >> 3, h = bh & 7;
  int d = threadIdx.x & 63, jg = threadIdx.x >> 6;
  int t0 = c * CSZ;
  float s = 0.f;
#pragma unroll
  for (int j = jg; j < CSZ; j += 4)
    s += v[(((size_t)b * Ld + t0 + j) * Hd + h) * Dd + d];
  red[threadIdx.x] = s;
  __syncthreads();
  if (jg == 0)
    csum[(size_t)blk * Dd + d] = red[d] + red[64 + d] + red[128 + d] + red[192 + d];
}

// ---------------------------------------------------------------------------
// Kernel 3b: exclusive scan of the NCHUNK chunk sums per (b,h,d).
// ---------------------------------------------------------------------------
__global__ void scan_chunks_kernel(float* __restrict__ csum) {
  int bh = blockIdx.x;
  int d = threadIdx.x;
  float acc = 0.f;
#pragma unroll 8
  for (int c = 0; c < NCHUNK; ++c) {
    size_t i = ((size_t)bh * NCHUNK + c) * Dd + d;
    float s = csum[i];
    csum[i] = acc;
    acc += s;
  }
}

// ---------------------------------------------------------------------------
// Kernel 3c: inclusive cumsum write.
// ---------------------------------------------------------------------------
__global__ void cumsum_write_kernel(const float* __restrict__ v,
                                    const float* __restrict__ csum,
                                    float* __restrict__ out) {
  int blk = blockIdx.x;
  int c = blk % NCHUNK, bh = blk / NCHUNK;
  int b = bh >> 3, h = bh & 7;
  int d = threadIdx.x;
  float acc = csum[(size_t)blk * Dd + d];
  int t0 = c * CSZ;
#pragma unroll 4
  for (int j = 0; j < CSZ; ++j) {
    size_t idx = (((size_t)b * Ld + t0 + j) * Hd + h) * Dd + d;
    acc += v[idx];
    out[idx] = acc;
  }
}

// ---------------------------------------------------------------------------
// Kernel 4a: masked scaled scores for all 40 selected queries x K tile.
// ---------------------------------------------------------------------------
__global__ __launch_bounds__(256) void scores_kernel(
    const float* __restrict__ q, const float* __restrict__ k,
    const int* __restrict__ topIdx, float* __restrict__ P) {
  __shared__ float qs[NTOP * QSTR];
  __shared__ float ks[KTILE * KSTR];
  __shared__ int ts[NTOP];
  int tid = threadIdx.x;
  int ksplit = blockIdx.x % KS;
  int bh = blockIdx.x / KS;
  int b = bh >> 3, h = bh & 7;
  int k0 = ksplit * KTILE;

  if (tid < NTOP) ts[tid] = topIdx[bh * NTOP + tid];
  __syncthreads();

  for (int i = tid; i < NTOP * 16; i += 256) {
    int u = i >> 4, p = i & 15;
    float4 qv = reinterpret_cast<const float4*>(
        q + (((size_t)b * Ld + ts[u]) * Hd + h) * Dd)[p];
    *reinterpret_cast<float4*>(&qs[u * QSTR + p * 4]) = qv;
  }
  for (int i = tid; i < KTILE * 16; i += 256) {
    int r = i >> 4, p = i & 15;
    float4 kv = reinterpret_cast<const float4*>(
        k + (((size_t)b * Ld + k0 + r) * Hd + h) * Dd)[p];
    *reinterpret_cast<float4*>(&ks[r * KSTR + p * 4]) = kv;
  }
  __syncthreads();

  int ug = tid & 7, kg = tid >> 3;
  int ub = ug * 5, kb = kg * 4;
  float acc[5][4] = {};
  for (int dd = 0; dd < Dd; dd += 4) {
    float4 kv[4], qv[5];
#pragma unroll
    for (int i = 0; i < 4; ++i)
      kv[i] = *reinterpret_cast<const float4*>(&ks[(kb + i) * KSTR + dd]);
#pragma unroll
    for (int i = 0; i < 5; ++i)
      qv[i] = *reinterpret_cast<const float4*>(&qs[(ub + i) * QSTR + dd]);
#pragma unroll
    for (int ui = 0; ui < 5; ++ui)
#pragma unroll
      for (int ki = 0; ki < 4; ++ki)
        acc[ui][ki] += qv[ui].x * kv[ki].x + qv[ui].y * kv[ki].y +
                       qv[ui].z * kv[ki].z + qv[ui].w * kv[ki].w;
  }

#pragma unroll
  for (int ui = 0; ui < 5; ++ui) {
    int u = ub + ui;
    int t = ts[u];
    float4 o;
    o.x = (k0 + kb + 0 <= t) ? acc[ui][0] * 0.125f : -INFINITY;
    o.y = (k0 + kb + 1 <= t) ? acc[ui][1] * 0.125f : -INFINITY;
    o.z = (k0 + kb + 2 <= t) ? acc[ui][2] * 0.125f : -INFINITY;
    o.w = (k0 + kb + 3 <= t) ? acc[ui][3] * 0.125f : -INFINITY;
    *reinterpret_cast<float4*>(&P[((size_t)bh * NTOP + u) * Ld + k0 + kb]) = o;
  }
}

// ---------------------------------------------------------------------------
// Kernel 4b: per selected row: max, exp in place, 1/denominator.
// ---------------------------------------------------------------------------
__global__ void softmax_prep_kernel(const int* __restrict__ topIdx,
                                    float* __restrict__ P,
                                    float* __restrict__ invden) {
  __shared__ float red[256];
  int row = blockIdx.x;
  int t = topIdx[row];
  int nk = t + 1;
  float* pr = P + (size_t)row * Ld;
  int tid = threadIdx.x;
  float lmax = -INFINITY;
  for (int i = tid; i < nk; i += 256) lmax = fmaxf(lmax, pr[i]);
  red[tid] = lmax;
  __syncthreads();
  for (int s = 128; s; s >>= 1) {
    if (tid < s) red[tid] = fmaxf(red[tid], red[tid + s]);
    __syncthreads();
  }
  float m = red[0];
  __syncthreads();
  float lsum = 0.f;
  for (int i = tid; i < nk; i += 256) {
    float p = __expf(pr[i] - m);
    pr[i] = p;
    lsum += p;
  }
  red[tid] = lsum;
  __syncthreads();
  for (int s = 128; s; s >>= 1) {
    if (tid < s) red[tid] += red[tid + s];
    __syncthreads();
  }
  if (tid == 0) invden[row] = 1.0f / red[0];
}

// ---------------------------------------------------------------------------
// Kernel 4c: split-K partial PV, float4-vectorized.
// ---------------------------------------------------------------------------
__global__ __launch_bounds__(256) void pv_partial_kernel(
    const float* __restrict__ v, const int* __restrict__ topIdx,
    const float* __restrict__ P, float* __restrict__ partial) {
  __shared__ float4 red4[64];  // 4 waves x 16 slots
  int vs = blockIdx.x % VS;
  int row = blockIdx.x / VS;
  int bh = row / NTOP;
  int b = bh >> 3, h = bh & 7;
  int t = topIdx[row];
  int lane = threadIdx.x & 63, wave = threadIdx.x >> 6;
  int d16 = lane & 15, kg = lane >> 4;
  int base = vs * VTILE + wave * 64;

  float4 acc = {0.f, 0.f, 0.f, 0.f};
  if (base <= t) {
    const float* pr = P + (size_t)row * Ld;
    const float* vb = v + ((size_t)b * Ld * Hd + h) * Dd;
#pragma unroll 4
    for (int it = 0; it < 16; ++it) {
      int kk = base + it * 4 + kg;
      if (kk <= t) {
        float p = pr[kk];
        float4 vv =
            reinterpret_cast<const float4*>(vb + (size_t)kk * Hd * Dd)[d16];
        acc.x += p * vv.x;
        acc.y += p * vv.y;
        acc.z += p * vv.z;
        acc.w += p * vv.w;
      }
    }
  }
  acc.x += __shfl_xor(acc.x, 16);
  acc.y += __shfl_xor(acc.y, 16);
  acc.z += __shfl_xor(acc.z, 16);
  acc.w += __shfl_xor(acc.w, 16);
  acc.x += __shfl_xor(acc.x, 32);
  acc.y += __shfl_xor(acc.y, 32);
  acc.z += __shfl_xor(acc.z, 32);
  acc.w += __shfl_xor(acc.w, 32);
  if (lane < 16) red4[wave * 16 + lane] = acc;
  __syncthreads();
  int tid = threadIdx.x;
  if (tid < 16) {
    float4 a = red4[tid], bb = red4[16 + tid], c = red4[32 + tid],
           dd4 = red4[48 + tid];
    float4 r;
    r.x = a.x + bb.x + c.x + dd4.x;
    r.y = a.y + bb.y + c.y + dd4.y;
    r.z = a.z + bb.z + c.z + dd4.z;
    r.w = a.w + bb.w + c.w + dd4.w;
    reinterpret_cast<float4*>(partial + (size_t)blockIdx.x * Dd)[tid] = r;
  }
}

// ---------------------------------------------------------------------------
// Kernel 4d: combine partials, normalize, scatter-overwrite output rows.
// ---------------------------------------------------------------------------
__global__ void pv_combine_kernel(const float* __restrict__ partial,
                                  const float* __restrict__ invden,
                                  const int* __restrict__ topIdx,
                                  float* __restrict__ out) {
  int row = blockIdx.x;
  int d = threadIdx.x;  // 64
  int bh = row / NTOP;
  int b = bh >> 3, h = bh & 7;
  int t = topIdx[row];
  float s = 0.f;
#pragma unroll
  for (int vs = 0; vs < VS; ++vs) s += partial[((size_t)row * VS + vs) * Dd + d];
  out[(((size_t)b * Ld + t) * Hd + h) * Dd + d] = s * invden[row];
}

// ---------------------------------------------------------------------------
// Fallback attention kernel if ws is too small.
// ---------------------------------------------------------------------------
__global__ void attn_update_kernel(const float* __restrict__ q,
                                   const float* __restrict__ k,
                                   const float* __restrict__ v,
                                   const int* __restrict__ topIdx,
                                   float* __restrict__ out) {
  __shared__ float sc[Ld];
  __shared__ float qs[Dd];
  __shared__ float red[256];
  int tid = threadIdx.x;
  int bh = blockIdx.x / NTOP;
  int b = bh >> 3, h = bh & 7;
  int t = topIdx[blockIdx.x];

  if (tid < Dd) qs[tid] = q[(((size_t)b * Ld + t) * Hd + h) * Dd + tid];
  __syncthreads();

  int nk = t + 1;
  const float4* qv4 = reinterpret_cast<const float4*>(qs);
  float lmax = -INFINITY;
  for (int kk = tid; kk < nk; kk += 256) {
    const float4* kr = reinterpret_cast<const float4*>(
        k + (((size_t)b * Ld + kk) * Hd + h) * Dd);
    float dot = 0.f;
#pragma unroll
    for (int j = 0; j < Dd / 4; ++j) {
      float4 a = qv4[j];
      float4 bb = kr[j];
      dot += a.x * bb.x + a.y * bb.y + a.z * bb.z + a.w * bb.w;
    }
    dot *= 0.125f;
    sc[kk] = dot;
    lmax = fmaxf(lmax, dot);
  }
  red[tid] = lmax;
  __syncthreads();
  for (int s = 128; s; s >>= 1) {
    if (tid < s) red[tid] = fmaxf(red[tid], red[tid + s]);
    __syncthreads();
  }
  float m = red[0];
  __syncthreads();
  float lsum = 0.f;
  for (int kk = tid; kk < nk; kk += 256) {
    float p = __expf(sc[kk] - m);
    sc[kk] = p;
    lsum += p;
  }
  red[tid] = lsum;
  __syncthreads();
  for (int s = 128; s; s >>= 1) {
    if (tid < s) red[tid] += red[tid + s];
    __syncthreads();
  }
  float inv_denom = 1.0f / red[0];
  __syncthreads();
  int d = tid & 63, kg = tid >> 6;
  float acc = 0.f;
  for (int kk = kg; kk < nk; kk += 4)
    acc += sc[kk] * v[(((size_t)b * Ld + kk) * Hd + h) * Dd + d];
  red[tid] = acc;
  __syncthreads();
  if (kg == 0) {
    float r = red[d] + red[64 + d] + red[128 + d] + red[192 + d];
    out[(((size_t)b * Ld + t) * Hd + h) * Dd + d] = r * inv_denom;
  }
}

// ---------------------------------------------------------------------------
extern "C" void kernel_launch(void* const* d_in, const int* in_sizes, int n_in,
                              void* d_out, int out_size, void* d_ws,
                              size_t ws_size, hipStream_t stream) {
  const float* q = (const float*)d_in[0];
  const float* k = (const float*)d_in[1];
  const float* v = (const float*)d_in[2];
  const int* ridx = (const int*)d_in[4];
  float* out = (float*)d_out;

  char* ws = (char*)d_ws;
  float* M = (float*)(ws + 0);              // 262144
  int* topIdx = (int*)(ws + 262144);        //   5120
  float* invden = (float*)(ws + 267264);    //   5120
  float* csum = (float*)(ws + 272384);      // 1048576
  float* partial = (float*)(ws + 1320960);  // 2621440
  float* P = (float*)(ws + 3942400);        // 10485760
  const size_t need_new = 3942400 + 10485760;

  compute_M_kernel<<<Bd * Hd * (Ld / 4), 256, 0, stream>>>(q, k, ridx, M);
  topk_kernel<<<Bd * Hd, 64, 0, stream>>>(M, topIdx);
  chunk_sums_kernel<<<Bd * Hd * NCHUNK, 256, 0, stream>>>(v, csum);
  scan_chunks_kernel<<<Bd * Hd, 64, 0, stream>>>(csum);
  cumsum_write_kernel<<<Bd * Hd * NCHUNK, 64, 0, stream>>>(v, csum, out);

  if (ws_size >= need_new) {
    scores_kernel<<<Bd * Hd * KS, 256, 0, stream>>>(q, k, topIdx, P);
    softmax_prep_kernel<<<Bd * Hd * NTOP, 256, 0, stream>>>(topIdx, P, invden);
    pv_partial_kernel<<<Bd * Hd * NTOP * VS, 256, 0, stream>>>(v, topIdx, P, partial);
    pv_combine_kernel<<<Bd * Hd * NTOP, 64, 0, stream>>>(partial, invden, topIdx, out);
  } else {
    attn_update_kernel<<<Bd * Hd * NTOP, 256, 0, stream>>>(q, k, v, topIdx, out);
  }
}

// Round 6
// 142.934 us; speedup vs baseline: 2.9599x; 1.0147x over previous
//
#include <hip/hip_runtime.h>

#define Bd 4
#define Hd 8
#define Ld 2048
#define Dd 64
#define Ud 40
#define NTOP 40

#define KS 16     // k-splits for scores kernel
#define KTILE 128 // Ld / KS
#define QSTR 68   // padded LDS stride (floats) for q rows
#define KSTR 68   // padded LDS stride (floats) for k rows
#define VS 8      // k-splits for PV
#define VTILE 256 // Ld / VS

// ---------------------------------------------------------------------------
// Kernel 1: M[b,h,q] = max_u(dot(q, k[ridx[q,u]])) - sum_u(dot)/L
// 4 lanes per sampled row (each lane: slots s,s+4,s+8,s+12 -> 16 floats,
// 16 fma), 16 rows in flight per pass, 3 passes for 40 samples.
// Only 2 shfl per sample. XCD-swizzled blockIdx.
// ---------------------------------------------------------------------------
__global__ void compute_M_kernel(const float* __restrict__ q,
                                 const float* __restrict__ k,
                                 const int* __restrict__ ridx,
                                 float* __restrict__ M) {
  const int nwg = Bd * Hd * (Ld / 4);  // 16384, %8==0 -> bijective swizzle
  int orig = blockIdx.x;
  int bid = (orig & 7) * (nwg >> 3) + (orig >> 3);

  int wave = threadIdx.x >> 6;
  int lane = threadIdx.x & 63;
  int qgroup = bid % (Ld / 4);
  int bh = bid / (Ld / 4);
  int b = bh >> 3, h = bh & 7;
  int qpos = qgroup * 4 + wave;

  int s = lane & 3;   // slot group (covers float4 slots s, s+4, s+8, s+12)
  int r = lane >> 2;  // row within pass, 0..15

  const float4* qrow4 = reinterpret_cast<const float4*>(
      q + (((size_t)b * Ld + qpos) * Hd + h) * Dd);
  float4 qv[4];
#pragma unroll
  for (int i = 0; i < 4; ++i) qv[i] = qrow4[s + 4 * i];

  const int* rbase = ridx + qpos * Ud;
  const float* kbase = k + (((size_t)b * Ld) * Hd + h) * Dd;

  float mx = -INFINITY, sm = 0.f;
#pragma unroll
  for (int p = 0; p < 3; ++p) {
    int u = p * 16 + r;
    if (u < Ud) {
      int kidx = rbase[u];
      const float4* kr =
          reinterpret_cast<const float4*>(kbase + (size_t)kidx * (Hd * Dd));
      float dot = 0.f;
#pragma unroll
      for (int i = 0; i < 4; ++i) {
        float4 kv = kr[s + 4 * i];
        dot += qv[i].x * kv.x + qv[i].y * kv.y + qv[i].z * kv.z +
               qv[i].w * kv.w;
      }
      // partners of xor 1,2 stay within the same row group (same activity)
      dot += __shfl_xor(dot, 1);
      dot += __shfl_xor(dot, 2);
      mx = fmaxf(mx, dot);
      sm += dot;
    }
  }
  // combine across the 16 row-groups; sum only s==0 lanes (values duplicated
  // across the 4 lanes of a group).
  float smv = (s == 0) ? sm : 0.f;
#pragma unroll
  for (int off = 4; off < 64; off <<= 1) {
    mx = fmaxf(mx, __shfl_xor(mx, off));
    smv += __shfl_xor(smv, off);
  }
  if (lane == 0) M[bh * Ld + qpos] = mx - smv * (1.0f / (float)Ld);
}

// ---------------------------------------------------------------------------
// Kernel 2: top-40 per (b,h), one wave. Per-lane top-3 cache of monotone u32
// keys; per iteration only a 6-step butterfly argmax; winner lane promotes
// its cache and rescans its 32 elements only when the cache is exhausted
// (filter: entries strictly preceding the current winner in (key desc, idx
// asc) order are exactly the already-selected ones).
// Output order is irrelevant: downstream treats topIdx as a set.
// ---------------------------------------------------------------------------
__global__ __launch_bounds__(64) void topk_kernel(const float* __restrict__ M,
                                                  int* __restrict__ topIdx) {
  int bh = blockIdx.x;
  int lane = threadIdx.x;
  const float* mrow = M + (size_t)bh * Ld;

  unsigned int key[32];
#pragma unroll
  for (int j = 0; j < 32; ++j) {
    unsigned int bits = __float_as_uint(mrow[lane + j * 64]);
    key[j] = (bits & 0x80000000u) ? ~bits : (bits | 0x80000000u);
  }

  const int ISENT = 1 << 30;
  unsigned int k0 = 0u, k1c = 0u, k2c = 0u;
  int i0 = ISENT, i1c = ISENT, i2c = ISENT;
#pragma unroll
  for (int j = 0; j < 32; ++j) {
    unsigned int kj = key[j];
    int idx = lane + j * 64;
    if (kj > k0) {
      k2c = k1c; i2c = i1c; k1c = k0; i1c = i0; k0 = kj; i0 = idx;
    } else if (kj > k1c) {
      k2c = k1c; i2c = i1c; k1c = kj; i1c = idx;
    } else if (kj > k2c) {
      k2c = kj; i2c = idx;
    }
  }

  for (int it = 0; it < NTOP; ++it) {
    unsigned int wk = k0;
    int wi = i0;
#pragma unroll
    for (int off = 1; off < 64; off <<= 1) {
      unsigned int ok = __shfl_xor(wk, off);
      int oi = __shfl_xor(wi, off);
      if (ok > wk || (ok == wk && oi < wi)) { wk = ok; wi = oi; }
    }
    if (lane == 0) topIdx[bh * NTOP + it] = wi;
    if (wi == i0) {  // this lane won (idx<->lane unique: idx%64==lane)
      k0 = k1c; i0 = i1c; k1c = k2c; i1c = i2c; k2c = 0u; i2c = ISENT;
      if (k0 == 0u) {  // cache exhausted: rebuild top-3 among remaining
        i0 = ISENT; i1c = ISENT; i2c = ISENT;
#pragma unroll
        for (int j = 0; j < 32; ++j) {
          unsigned int kj = key[j];
          int idx = lane + j * 64;
          bool valid = (kj < wk) || (kj == wk && idx > wi);
          kj = valid ? kj : 0u;
          if (kj > k0) {
            k2c = k1c; i2c = i1c; k1c = k0; i1c = i0; k0 = kj; i0 = idx;
          } else if (kj > k1c) {
            k2c = k1c; i2c = i1c; k1c = kj; i1c = idx;
          } else if (kj > k2c) {
            k2c = kj; i2c = idx;
          }
        }
      }
    }
  }
}

// ---------------------------------------------------------------------------
// Kernel 3: fused cumsum of V along L per (b,h). 16 waves x 128-t ranges;
// pass1 range sums -> LDS; per-wave exclusive offset; pass2 prefix + write.
// ---------------------------------------------------------------------------
__global__ __launch_bounds__(1024) void vcumsum_kernel(
    const float* __restrict__ v, float* __restrict__ out) {
  __shared__ float tot[16][64];
  int bh = blockIdx.x;
  int b = bh >> 3, h = bh & 7;
  int lane = threadIdx.x & 63, w = threadIdx.x >> 6;
  const float* vb = v + (((size_t)b * Ld) * Hd + h) * Dd + lane;
  float* ob = out + (((size_t)b * Ld) * Hd + h) * Dd + lane;
  int t0 = w * 128;

  float acc = 0.f;
#pragma unroll 16
  for (int j = 0; j < 128; ++j) acc += vb[(size_t)(t0 + j) * (Hd * Dd)];
  tot[w][lane] = acc;
  __syncthreads();

  float run = 0.f;
  for (int p = 0; p < w; ++p) run += tot[p][lane];
#pragma unroll 8
  for (int j = 0; j < 128; ++j) {
    run += vb[(size_t)(t0 + j) * (Hd * Dd)];
    ob[(size_t)(t0 + j) * (Hd * Dd)] = run;
  }
}

// ---------------------------------------------------------------------------
// Kernel 4a: masked scaled scores for all 40 selected queries x K tile.
// ---------------------------------------------------------------------------
__global__ __launch_bounds__(256) void scores_kernel(
    const float* __restrict__ q, const float* __restrict__ k,
    const int* __restrict__ topIdx, float* __restrict__ P) {
  __shared__ float qs[NTOP * QSTR];
  __shared__ float ks[KTILE * KSTR];
  __shared__ int ts[NTOP];
  int tid = threadIdx.x;
  int ksplit = blockIdx.x % KS;
  int bh = blockIdx.x / KS;
  int b = bh >> 3, h = bh & 7;
  int k0 = ksplit * KTILE;

  if (tid < NTOP) ts[tid] = topIdx[bh * NTOP + tid];
  __syncthreads();

  for (int i = tid; i < NTOP * 16; i += 256) {
    int u = i >> 4, p = i & 15;
    float4 qv = reinterpret_cast<const float4*>(
        q + (((size_t)b * Ld + ts[u]) * Hd + h) * Dd)[p];
    *reinterpret_cast<float4*>(&qs[u * QSTR + p * 4]) = qv;
  }
  for (int i = tid; i < KTILE * 16; i += 256) {
    int r = i >> 4, p = i & 15;
    float4 kv = reinterpret_cast<const float4*>(
        k + (((size_t)b * Ld + k0 + r) * Hd + h) * Dd)[p];
    *reinterpret_cast<float4*>(&ks[r * KSTR + p * 4]) = kv;
  }
  __syncthreads();

  int ug = tid & 7, kg = tid >> 3;
  int ub = ug * 5, kb = kg * 4;
  float acc[5][4] = {};
  for (int dd = 0; dd < Dd; dd += 4) {
    float4 kv[4], qv[5];
#pragma unroll
    for (int i = 0; i < 4; ++i)
      kv[i] = *reinterpret_cast<const float4*>(&ks[(kb + i) * KSTR + dd]);
#pragma unroll
    for (int i = 0; i < 5; ++i)
      qv[i] = *reinterpret_cast<const float4*>(&qs[(ub + i) * QSTR + dd]);
#pragma unroll
    for (int ui = 0; ui < 5; ++ui)
#pragma unroll
      for (int ki = 0; ki < 4; ++ki)
        acc[ui][ki] += qv[ui].x * kv[ki].x + qv[ui].y * kv[ki].y +
                       qv[ui].z * kv[ki].z + qv[ui].w * kv[ki].w;
  }

#pragma unroll
  for (int ui = 0; ui < 5; ++ui) {
    int u = ub + ui;
    int t = ts[u];
    float4 o;
    o.x = (k0 + kb + 0 <= t) ? acc[ui][0] * 0.125f : -INFINITY;
    o.y = (k0 + kb + 1 <= t) ? acc[ui][1] * 0.125f : -INFINITY;
    o.z = (k0 + kb + 2 <= t) ? acc[ui][2] * 0.125f : -INFINITY;
    o.w = (k0 + kb + 3 <= t) ? acc[ui][3] * 0.125f : -INFINITY;
    *reinterpret_cast<float4*>(&P[((size_t)bh * NTOP + u) * Ld + k0 + kb]) = o;
  }
}

// ---------------------------------------------------------------------------
// Kernel 4b: per selected row: max, exp in place, 1/denominator.
// ---------------------------------------------------------------------------
__global__ void softmax_prep_kernel(const int* __restrict__ topIdx,
                                    float* __restrict__ P,
                                    float* __restrict__ invden) {
  __shared__ float red[256];
  int row = blockIdx.x;
  int t = topIdx[row];
  int nk = t + 1;
  float* pr = P + (size_t)row * Ld;
  int tid = threadIdx.x;
  float lmax = -INFINITY;
  for (int i = tid; i < nk; i += 256) lmax = fmaxf(lmax, pr[i]);
  red[tid] = lmax;
  __syncthreads();
  for (int s = 128; s; s >>= 1) {
    if (tid < s) red[tid] = fmaxf(red[tid], red[tid + s]);
    __syncthreads();
  }
  float m = red[0];
  __syncthreads();
  float lsum = 0.f;
  for (int i = tid; i < nk; i += 256) {
    float p = __expf(pr[i] - m);
    pr[i] = p;
    lsum += p;
  }
  red[tid] = lsum;
  __syncthreads();
  for (int s = 128; s; s >>= 1) {
    if (tid < s) red[tid] += red[tid + s];
    __syncthreads();
  }
  if (tid == 0) invden[row] = 1.0f / red[0];
}

// ---------------------------------------------------------------------------
// Kernel 4c: split-K partial PV, float4-vectorized.
// ---------------------------------------------------------------------------
__global__ __launch_bounds__(256) void pv_partial_kernel(
    const float* __restrict__ v, const int* __restrict__ topIdx,
    const float* __restrict__ P, float* __restrict__ partial) {
  __shared__ float4 red4[64];  // 4 waves x 16 slots
  int vs = blockIdx.x % VS;
  int row = blockIdx.x / VS;
  int bh = row / NTOP;
  int b = bh >> 3, h = bh & 7;
  int t = topIdx[row];
  int lane = threadIdx.x & 63, wave = threadIdx.x >> 6;
  int d16 = lane & 15, kg = lane >> 4;
  int base = vs * VTILE + wave * 64;

  float4 acc = {0.f, 0.f, 0.f, 0.f};
  if (base <= t) {
    const float* pr = P + (size_t)row * Ld;
    const float* vb = v + ((size_t)b * Ld * Hd + h) * Dd;
#pragma unroll 4
    for (int it = 0; it < 16; ++it) {
      int kk = base + it * 4 + kg;
      if (kk <= t) {
        float p = pr[kk];
        float4 vv =
            reinterpret_cast<const float4*>(vb + (size_t)kk * Hd * Dd)[d16];
        acc.x += p * vv.x;
        acc.y += p * vv.y;
        acc.z += p * vv.z;
        acc.w += p * vv.w;
      }
    }
  }
  acc.x += __shfl_xor(acc.x, 16);
  acc.y += __shfl_xor(acc.y, 16);
  acc.z += __shfl_xor(acc.z, 16);
  acc.w += __shfl_xor(acc.w, 16);
  acc.x += __shfl_xor(acc.x, 32);
  acc.y += __shfl_xor(acc.y, 32);
  acc.z += __shfl_xor(acc.z, 32);
  acc.w += __shfl_xor(acc.w, 32);
  if (lane < 16) red4[wave * 16 + lane] = acc;
  __syncthreads();
  int tid = threadIdx.x;
  if (tid < 16) {
    float4 a = red4[tid], bb = red4[16 + tid], c = red4[32 + tid],
           dd4 = red4[48 + tid];
    float4 r;
    r.x = a.x + bb.x + c.x + dd4.x;
    r.y = a.y + bb.y + c.y + dd4.y;
    r.z = a.z + bb.z + c.z + dd4.z;
    r.w = a.w + bb.w + c.w + dd4.w;
    reinterpret_cast<float4*>(partial + (size_t)blockIdx.x * Dd)[tid] = r;
  }
}

// ---------------------------------------------------------------------------
// Kernel 4d: combine partials, normalize, scatter-overwrite output rows.
// ---------------------------------------------------------------------------
__global__ void pv_combine_kernel(const float* __restrict__ partial,
                                  const float* __restrict__ invden,
                                  const int* __restrict__ topIdx,
                                  float* __restrict__ out) {
  int row = blockIdx.x;
  int d = threadIdx.x;  // 64
  int bh = row / NTOP;
  int b = bh >> 3, h = bh & 7;
  int t = topIdx[row];
  float s = 0.f;
#pragma unroll
  for (int vs = 0; vs < VS; ++vs) s += partial[((size_t)row * VS + vs) * Dd + d];
  out[(((size_t)b * Ld + t) * Hd + h) * Dd + d] = s * invden[row];
}

// ---------------------------------------------------------------------------
// Fallback attention kernel if ws is too small.
// ---------------------------------------------------------------------------
__global__ void attn_update_kernel(const float* __restrict__ q,
                                   const float* __restrict__ k,
                                   const float* __restrict__ v,
                                   const int* __restrict__ topIdx,
                                   float* __restrict__ out) {
  __shared__ float sc[Ld];
  __shared__ float qs[Dd];
  __shared__ float red[256];
  int tid = threadIdx.x;
  int bh = blockIdx.x / NTOP;
  int b = bh >> 3, h = bh & 7;
  int t = topIdx[blockIdx.x];

  if (tid < Dd) qs[tid] = q[(((size_t)b * Ld + t) * Hd + h) * Dd + tid];
  __syncthreads();

  int nk = t + 1;
  const float4* qv4 = reinterpret_cast<const float4*>(qs);
  float lmax = -INFINITY;
  for (int kk = tid; kk < nk; kk += 256) {
    const float4* kr = reinterpret_cast<const float4*>(
        k + (((size_t)b * Ld + kk) * Hd + h) * Dd);
    float dot = 0.f;
#pragma unroll
    for (int j = 0; j < Dd / 4; ++j) {
      float4 a = qv4[j];
      float4 bb = kr[j];
      dot += a.x * bb.x + a.y * bb.y + a.z * bb.z + a.w * bb.w;
    }
    dot *= 0.125f;
    sc[kk] = dot;
    lmax = fmaxf(lmax, dot);
  }
  red[tid] = lmax;
  __syncthreads();
  for (int s = 128; s; s >>= 1) {
    if (tid < s) red[tid] = fmaxf(red[tid], red[tid + s]);
    __syncthreads();
  }
  float m = red[0];
  __syncthreads();
  float lsum = 0.f;
  for (int kk = tid; kk < nk; kk += 256) {
    float p = __expf(sc[kk] - m);
    sc[kk] = p;
    lsum += p;
  }
  red[tid] = lsum;
  __syncthreads();
  for (int s = 128; s; s >>= 1) {
    if (tid < s) red[tid] += red[tid + s];
    __syncthreads();
  }
  float inv_denom = 1.0f / red[0];
  __syncthreads();
  int d = tid & 63, kg = tid >> 6;
  float acc = 0.f;
  for (int kk = kg; kk < nk; kk += 4)
    acc += sc[kk] * v[(((size_t)b * Ld + kk) * Hd + h) * Dd + d];
  red[tid] = acc;
  __syncthreads();
  if (kg == 0) {
    float r = red[d] + red[64 + d] + red[128 + d] + red[192 + d];
    out[(((size_t)b * Ld + t) * Hd + h) * Dd + d] = r * inv_denom;
  }
}

// ---------------------------------------------------------------------------
extern "C" void kernel_launch(void* const* d_in, const int* in_sizes, int n_in,
                              void* d_out, int out_size, void* d_ws,
                              size_t ws_size, hipStream_t stream) {
  const float* q = (const float*)d_in[0];
  const float* k = (const float*)d_in[1];
  const float* v = (const float*)d_in[2];
  const int* ridx = (const int*)d_in[4];
  float* out = (float*)d_out;

  char* ws = (char*)d_ws;
  float* M = (float*)(ws + 0);              // 262144
  int* topIdx = (int*)(ws + 262144);        //   5120
  float* invden = (float*)(ws + 267264);    //   5120
  float* partial = (float*)(ws + 1320960);  // 2621440
  float* P = (float*)(ws + 3942400);        // 10485760
  const size_t need_new = 3942400 + 10485760;

  compute_M_kernel<<<Bd * Hd * (Ld / 4), 256, 0, stream>>>(q, k, ridx, M);
  topk_kernel<<<Bd * Hd, 64, 0, stream>>>(M, topIdx);
  vcumsum_kernel<<<Bd * Hd, 1024, 0, stream>>>(v, out);

  if (ws_size >= need_new) {
    scores_kernel<<<Bd * Hd * KS, 256, 0, stream>>>(q, k, topIdx, P);
    softmax_prep_kernel<<<Bd * Hd * NTOP, 256, 0, stream>>>(topIdx, P, invden);
    pv_partial_kernel<<<Bd * Hd * NTOP * VS, 256, 0, stream>>>(v, topIdx, P, partial);
    pv_combine_kernel<<<Bd * Hd * NTOP, 64, 0, stream>>>(partial, invden, topIdx, out);
  } else {
    attn_update_kernel<<<Bd * Hd * NTOP, 256, 0, stream>>>(q, k, v, topIdx, out);
  }
}

// Round 7
// 134.851 us; speedup vs baseline: 3.1373x; 1.0599x over previous
//
#include <hip/hip_runtime.h>

#define Bd 4
#define Hd 8
#define Ld 2048
#define Dd 64
#define Ud 40
#define NTOP 40
#define NCHUNK 128
#define CSZ 16   // Ld / NCHUNK

#define KS 16     // k-splits for scores kernel
#define KTILE 128 // Ld / KS
#define QSTR 68   // padded LDS stride (floats) for q rows
#define KSTR 68   // padded LDS stride (floats) for k rows
#define VS 8      // k-splits for PV
#define VTILE 256 // Ld / VS

// ---------------------------------------------------------------------------
// Kernel 1: M[b,h,q] = max_u(dot(q, k[ridx[q,u]])) - sum_u(dot)/L
// One wave per (b,l) covering ALL 8 heads: ridx is shared across b,h and
// K[b][l][*][*] is 2KB contiguous -> each sampled row = 2 perfectly coalesced
// dwordx4 loads. lane = h*8 + slice(8 floats). Sample index is wave-uniform
// (readlane). XCD swizzle: each XCD owns one b's l-range (K[b]=4MB=its L2).
// ---------------------------------------------------------------------------
__global__ __launch_bounds__(256) void compute_M_kernel(
    const float* __restrict__ q, const float* __restrict__ k,
    const int* __restrict__ ridx, float* __restrict__ M) {
  const int nblk = Bd * Ld / 4;  // 2048 blocks, %8==0 -> bijective swizzle
  int orig = blockIdx.x;
  int bid = (orig & 7) * (nblk >> 3) + (orig >> 3);
  int gw = bid * 4 + (threadIdx.x >> 6);  // wave id = (b,l)
  int lane = threadIdx.x & 63;
  int hg = lane >> 3;  // head
  int s8 = lane & 7;   // 8-float slice within head row
  int b = gw >> 11;
  int l = gw & (Ld - 1);

  const float* qrow = q + ((size_t)b * Ld + l) * (Hd * Dd) + lane * 8;
  float4 q0 = *reinterpret_cast<const float4*>(qrow);
  float4 q1 = *reinterpret_cast<const float4*>(qrow + 4);

  int rv = 0;
  if (lane < Ud) rv = ridx[l * Ud + lane];

  const float* kb = k + (size_t)b * Ld * (Hd * Dd);

  float mx = -INFINITY, sm = 0.f;
#pragma unroll 8
  for (int u = 0; u < Ud; ++u) {
    int kidx = __shfl(rv, u);  // wave-uniform
    const float* kr = kb + (size_t)kidx * (Hd * Dd) + lane * 8;
    float4 k0 = *reinterpret_cast<const float4*>(kr);
    float4 k1 = *reinterpret_cast<const float4*>(kr + 4);
    float dot = q0.x * k0.x + q0.y * k0.y + q0.z * k0.z + q0.w * k0.w +
                q1.x * k1.x + q1.y * k1.y + q1.z * k1.z + q1.w * k1.w;
    dot += __shfl_xor(dot, 1);
    dot += __shfl_xor(dot, 2);
    dot += __shfl_xor(dot, 4);  // all 8 lanes of the head hold full dot
    mx = fmaxf(mx, dot);
    sm += dot;
  }
  if (s8 == 0)
    M[((size_t)b * Hd + hg) * Ld + l] = mx - sm * (1.0f / (float)Ld);
}

// ---------------------------------------------------------------------------
// Kernel 2: top-40 per (b,h), one wave, per-lane top-3 cache (round-6 ver).
// ---------------------------------------------------------------------------
__global__ __launch_bounds__(64) void topk_kernel(const float* __restrict__ M,
                                                  int* __restrict__ topIdx) {
  int bh = blockIdx.x;
  int lane = threadIdx.x;
  const float* mrow = M + (size_t)bh * Ld;

  unsigned int key[32];
#pragma unroll
  for (int j = 0; j < 32; ++j) {
    unsigned int bits = __float_as_uint(mrow[lane + j * 64]);
    key[j] = (bits & 0x80000000u) ? ~bits : (bits | 0x80000000u);
  }

  const int ISENT = 1 << 30;
  unsigned int k0 = 0u, k1c = 0u, k2c = 0u;
  int i0 = ISENT, i1c = ISENT, i2c = ISENT;
#pragma unroll
  for (int j = 0; j < 32; ++j) {
    unsigned int kj = key[j];
    int idx = lane + j * 64;
    if (kj > k0) {
      k2c = k1c; i2c = i1c; k1c = k0; i1c = i0; k0 = kj; i0 = idx;
    } else if (kj > k1c) {
      k2c = k1c; i2c = i1c; k1c = kj; i1c = idx;
    } else if (kj > k2c) {
      k2c = kj; i2c = idx;
    }
  }

  for (int it = 0; it < NTOP; ++it) {
    unsigned int wk = k0;
    int wi = i0;
#pragma unroll
    for (int off = 1; off < 64; off <<= 1) {
      unsigned int ok = __shfl_xor(wk, off);
      int oi = __shfl_xor(wi, off);
      if (ok > wk || (ok == wk && oi < wi)) { wk = ok; wi = oi; }
    }
    if (lane == 0) topIdx[bh * NTOP + it] = wi;
    if (wi == i0) {
      k0 = k1c; i0 = i1c; k1c = k2c; i1c = i2c; k2c = 0u; i2c = ISENT;
      if (k0 == 0u) {
        i0 = ISENT; i1c = ISENT; i2c = ISENT;
#pragma unroll
        for (int j = 0; j < 32; ++j) {
          unsigned int kj = key[j];
          int idx = lane + j * 64;
          bool valid = (kj < wk) || (kj == wk && idx > wi);
          kj = valid ? kj : 0u;
          if (kj > k0) {
            k2c = k1c; i2c = i1c; k1c = k0; i1c = i0; k0 = kj; i0 = idx;
          } else if (kj > k1c) {
            k2c = k1c; i2c = i1c; k1c = kj; i1c = idx;
          } else if (kj > k2c) {
            k2c = kj; i2c = idx;
          }
        }
      }
    }
  }
}

// ---------------------------------------------------------------------------
// Kernel 3a: per-chunk sums of V along L. Block (256 thr) per (b,h,chunk).
// ---------------------------------------------------------------------------
__global__ void chunk_sums_kernel(const float* __restrict__ v,
                                  float* __restrict__ csum) {
  __shared__ float red[256];
  int blk = blockIdx.x;
  int c = blk % NCHUNK, bh = blk / NCHUNK;
  int b = bh >> 3, h = bh & 7;
  int d = threadIdx.x & 63, jg = threadIdx.x >> 6;
  int t0 = c * CSZ;
  float s = 0.f;
#pragma unroll
  for (int j = jg; j < CSZ; j += 4)
    s += v[(((size_t)b * Ld + t0 + j) * Hd + h) * Dd + d];
  red[threadIdx.x] = s;
  __syncthreads();
  if (jg == 0)
    csum[(size_t)blk * Dd + d] = red[d] + red[64 + d] + red[128 + d] + red[192 + d];
}

// ---------------------------------------------------------------------------
// Kernel 3b: exclusive scan of the NCHUNK chunk sums per (b,h,d).
// ---------------------------------------------------------------------------
__global__ void scan_chunks_kernel(float* __restrict__ csum) {
  int bh = blockIdx.x;
  int d = threadIdx.x;
  float acc = 0.f;
#pragma unroll 8
  for (int c = 0; c < NCHUNK; ++c) {
    size_t i = ((size_t)bh * NCHUNK + c) * Dd + d;
    float s = csum[i];
    csum[i] = acc;
    acc += s;
  }
}

// ---------------------------------------------------------------------------
// Kernel 3c: inclusive cumsum write.
// ---------------------------------------------------------------------------
__global__ void cumsum_write_kernel(const float* __restrict__ v,
                                    const float* __restrict__ csum,
                                    float* __restrict__ out) {
  int blk = blockIdx.x;
  int c = blk % NCHUNK, bh = blk / NCHUNK;
  int b = bh >> 3, h = bh & 7;
  int d = threadIdx.x;
  float acc = csum[(size_t)blk * Dd + d];
  int t0 = c * CSZ;
#pragma unroll 4
  for (int j = 0; j < CSZ; ++j) {
    size_t idx = (((size_t)b * Ld + t0 + j) * Hd + h) * Dd + d;
    acc += v[idx];
    out[idx] = acc;
  }
}

// ---------------------------------------------------------------------------
// Kernel 4a: masked scaled scores for all 40 selected queries x K tile.
// ---------------------------------------------------------------------------
__global__ __launch_bounds__(256) void scores_kernel(
    const float* __restrict__ q, const float* __restrict__ k,
    const int* __restrict__ topIdx, float* __restrict__ P) {
  __shared__ float qs[NTOP * QSTR];
  __shared__ float ks[KTILE * KSTR];
  __shared__ int ts[NTOP];
  int tid = threadIdx.x;
  int ksplit = blockIdx.x % KS;
  int bh = blockIdx.x / KS;
  int b = bh >> 3, h = bh & 7;
  int k0 = ksplit * KTILE;

  if (tid < NTOP) ts[tid] = topIdx[bh * NTOP + tid];
  __syncthreads();

  for (int i = tid; i < NTOP * 16; i += 256) {
    int u = i >> 4, p = i & 15;
    float4 qv = reinterpret_cast<const float4*>(
        q + (((size_t)b * Ld + ts[u]) * Hd + h) * Dd)[p];
    *reinterpret_cast<float4*>(&qs[u * QSTR + p * 4]) = qv;
  }
  for (int i = tid; i < KTILE * 16; i += 256) {
    int r = i >> 4, p = i & 15;
    float4 kv = reinterpret_cast<const float4*>(
        k + (((size_t)b * Ld + k0 + r) * Hd + h) * Dd)[p];
    *reinterpret_cast<float4*>(&ks[r * KSTR + p * 4]) = kv;
  }
  __syncthreads();

  int ug = tid & 7, kg = tid >> 3;
  int ub = ug * 5, kb = kg * 4;
  float acc[5][4] = {};
  for (int dd = 0; dd < Dd; dd += 4) {
    float4 kv[4], qv[5];
#pragma unroll
    for (int i = 0; i < 4; ++i)
      kv[i] = *reinterpret_cast<const float4*>(&ks[(kb + i) * KSTR + dd]);
#pragma unroll
    for (int i = 0; i < 5; ++i)
      qv[i] = *reinterpret_cast<const float4*>(&qs[(ub + i) * QSTR + dd]);
#pragma unroll
    for (int ui = 0; ui < 5; ++ui)
#pragma unroll
      for (int ki = 0; ki < 4; ++ki)
        acc[ui][ki] += qv[ui].x * kv[ki].x + qv[ui].y * kv[ki].y +
                       qv[ui].z * kv[ki].z + qv[ui].w * kv[ki].w;
  }

#pragma unroll
  for (int ui = 0; ui < 5; ++ui) {
    int u = ub + ui;
    int t = ts[u];
    float4 o;
    o.x = (k0 + kb + 0 <= t) ? acc[ui][0] * 0.125f : -INFINITY;
    o.y = (k0 + kb + 1 <= t) ? acc[ui][1] * 0.125f : -INFINITY;
    o.z = (k0 + kb + 2 <= t) ? acc[ui][2] * 0.125f : -INFINITY;
    o.w = (k0 + kb + 3 <= t) ? acc[ui][3] * 0.125f : -INFINITY;
    *reinterpret_cast<float4*>(&P[((size_t)bh * NTOP + u) * Ld + k0 + kb]) = o;
  }
}

// ---------------------------------------------------------------------------
// Kernel 4b: per selected row: max, exp in place, 1/denominator.
// ---------------------------------------------------------------------------
__global__ void softmax_prep_kernel(const int* __restrict__ topIdx,
                                    float* __restrict__ P,
                                    float* __restrict__ invden) {
  __shared__ float red[256];
  int row = blockIdx.x;
  int t = topIdx[row];
  int nk = t + 1;
  float* pr = P + (size_t)row * Ld;
  int tid = threadIdx.x;
  float lmax = -INFINITY;
  for (int i = tid; i < nk; i += 256) lmax = fmaxf(lmax, pr[i]);
  red[tid] = lmax;
  __syncthreads();
  for (int s = 128; s; s >>= 1) {
    if (tid < s) red[tid] = fmaxf(red[tid], red[tid + s]);
    __syncthreads();
  }
  float m = red[0];
  __syncthreads();
  float lsum = 0.f;
  for (int i = tid; i < nk; i += 256) {
    float p = __expf(pr[i] - m);
    pr[i] = p;
    lsum += p;
  }
  red[tid] = lsum;
  __syncthreads();
  for (int s = 128; s; s >>= 1) {
    if (tid < s) red[tid] += red[tid + s];
    __syncthreads();
  }
  if (tid == 0) invden[row] = 1.0f / red[0];
}

// ---------------------------------------------------------------------------
// Kernel 4c: split-K partial PV, float4-vectorized.
// ---------------------------------------------------------------------------
__global__ __launch_bounds__(256) void pv_partial_kernel(
    const float* __restrict__ v, const int* __restrict__ topIdx,
    const float* __restrict__ P, float* __restrict__ partial) {
  __shared__ float4 red4[64];  // 4 waves x 16 slots
  int vs = blockIdx.x % VS;
  int row = blockIdx.x / VS;
  int bh = row / NTOP;
  int b = bh >> 3, h = bh & 7;
  int t = topIdx[row];
  int lane = threadIdx.x & 63, wave = threadIdx.x >> 6;
  int d16 = lane & 15, kg = lane >> 4;
  int base = vs * VTILE + wave * 64;

  float4 acc = {0.f, 0.f, 0.f, 0.f};
  if (base <= t) {
    const float* pr = P + (size_t)row * Ld;
    const float* vb = v + ((size_t)b * Ld * Hd + h) * Dd;
#pragma unroll 4
    for (int it = 0; it < 16; ++it) {
      int kk = base + it * 4 + kg;
      if (kk <= t) {
        float p = pr[kk];
        float4 vv =
            reinterpret_cast<const float4*>(vb + (size_t)kk * Hd * Dd)[d16];
        acc.x += p * vv.x;
        acc.y += p * vv.y;
        acc.z += p * vv.z;
        acc.w += p * vv.w;
      }
    }
  }
  acc.x += __shfl_xor(acc.x, 16);
  acc.y += __shfl_xor(acc.y, 16);
  acc.z += __shfl_xor(acc.z, 16);
  acc.w += __shfl_xor(acc.w, 16);
  acc.x += __shfl_xor(acc.x, 32);
  acc.y += __shfl_xor(acc.y, 32);
  acc.z += __shfl_xor(acc.z, 32);
  acc.w += __shfl_xor(acc.w, 32);
  if (lane < 16) red4[wave * 16 + lane] = acc;
  __syncthreads();
  int tid = threadIdx.x;
  if (tid < 16) {
    float4 a = red4[tid], bb = red4[16 + tid], c = red4[32 + tid],
           dd4 = red4[48 + tid];
    float4 r;
    r.x = a.x + bb.x + c.x + dd4.x;
    r.y = a.y + bb.y + c.y + dd4.y;
    r.z = a.z + bb.z + c.z + dd4.z;
    r.w = a.w + bb.w + c.w + dd4.w;
    reinterpret_cast<float4*>(partial + (size_t)blockIdx.x * Dd)[tid] = r;
  }
}

// ---------------------------------------------------------------------------
// Kernel 4d: combine partials, normalize, scatter-overwrite output rows.
// ---------------------------------------------------------------------------
__global__ void pv_combine_kernel(const float* __restrict__ partial,
                                  const float* __restrict__ invden,
                                  const int* __restrict__ topIdx,
                                  float* __restrict__ out) {
  int row = blockIdx.x;
  int d = threadIdx.x;  // 64
  int bh = row / NTOP;
  int b = bh >> 3, h = bh & 7;
  int t = topIdx[row];
  float s = 0.f;
#pragma unroll
  for (int vs = 0; vs < VS; ++vs) s += partial[((size_t)row * VS + vs) * Dd + d];
  out[(((size_t)b * Ld + t) * Hd + h) * Dd + d] = s * invden[row];
}

// ---------------------------------------------------------------------------
// Fallback attention kernel if ws is too small.
// ---------------------------------------------------------------------------
__global__ void attn_update_kernel(const float* __restrict__ q,
                                   const float* __restrict__ k,
                                   const float* __restrict__ v,
                                   const int* __restrict__ topIdx,
                                   float* __restrict__ out) {
  __shared__ float sc[Ld];
  __shared__ float qs[Dd];
  __shared__ float red[256];
  int tid = threadIdx.x;
  int bh = blockIdx.x / NTOP;
  int b = bh >> 3, h = bh & 7;
  int t = topIdx[blockIdx.x];

  if (tid < Dd) qs[tid] = q[(((size_t)b * Ld + t) * Hd + h) * Dd + tid];
  __syncthreads();

  int nk = t + 1;
  const float4* qv4 = reinterpret_cast<const float4*>(qs);
  float lmax = -INFINITY;
  for (int kk = tid; kk < nk; kk += 256) {
    const float4* kr = reinterpret_cast<const float4*>(
        k + (((size_t)b * Ld + kk) * Hd + h) * Dd);
    float dot = 0.f;
#pragma unroll
    for (int j = 0; j < Dd / 4; ++j) {
      float4 a = qv4[j];
      float4 bb = kr[j];
      dot += a.x * bb.x + a.y * bb.y + a.z * bb.z + a.w * bb.w;
    }
    dot *= 0.125f;
    sc[kk] = dot;
    lmax = fmaxf(lmax, dot);
  }
  red[tid] = lmax;
  __syncthreads();
  for (int s = 128; s; s >>= 1) {
    if (tid < s) red[tid] = fmaxf(red[tid], red[tid + s]);
    __syncthreads();
  }
  float m = red[0];
  __syncthreads();
  float lsum = 0.f;
  for (int kk = tid; kk < nk; kk += 256) {
    float p = __expf(sc[kk] - m);
    sc[kk] = p;
    lsum += p;
  }
  red[tid] = lsum;
  __syncthreads();
  for (int s = 128; s; s >>= 1) {
    if (tid < s) red[tid] += red[tid + s];
    __syncthreads();
  }
  float inv_denom = 1.0f / red[0];
  __syncthreads();
  int d = tid & 63, kg = tid >> 6;
  float acc = 0.f;
  for (int kk = kg; kk < nk; kk += 4)
    acc += sc[kk] * v[(((size_t)b * Ld + kk) * Hd + h) * Dd + d];
  red[tid] = acc;
  __syncthreads();
  if (kg == 0) {
    float r = red[d] + red[64 + d] + red[128 + d] + red[192 + d];
    out[(((size_t)b * Ld + t) * Hd + h) * Dd + d] = r * inv_denom;
  }
}

// ---------------------------------------------------------------------------
extern "C" void kernel_launch(void* const* d_in, const int* in_sizes, int n_in,
                              void* d_out, int out_size, void* d_ws,
                              size_t ws_size, hipStream_t stream) {
  const float* q = (const float*)d_in[0];
  const float* k = (const float*)d_in[1];
  const float* v = (const float*)d_in[2];
  const int* ridx = (const int*)d_in[4];
  float* out = (float*)d_out;

  char* ws = (char*)d_ws;
  float* M = (float*)(ws + 0);              // 262144
  int* topIdx = (int*)(ws + 262144);        //   5120
  float* invden = (float*)(ws + 267264);    //   5120
  float* csum = (float*)(ws + 272384);      // 1048576
  float* partial = (float*)(ws + 1320960);  // 2621440
  float* P = (float*)(ws + 3942400);        // 10485760
  const size_t need_new = 3942400 + 10485760;

  compute_M_kernel<<<Bd * Ld / 4, 256, 0, stream>>>(q, k, ridx, M);
  topk_kernel<<<Bd * Hd, 64, 0, stream>>>(M, topIdx);
  chunk_sums_kernel<<<Bd * Hd * NCHUNK, 256, 0, stream>>>(v, csum);
  scan_chunks_kernel<<<Bd * Hd, 64, 0, stream>>>(csum);
  cumsum_write_kernel<<<Bd * Hd * NCHUNK, 64, 0, stream>>>(v, csum, out);

  if (ws_size >= need_new) {
    scores_kernel<<<Bd * Hd * KS, 256, 0, stream>>>(q, k, topIdx, P);
    softmax_prep_kernel<<<Bd * Hd * NTOP, 256, 0, stream>>>(topIdx, P, invden);
    pv_partial_kernel<<<Bd * Hd * NTOP * VS, 256, 0, stream>>>(v, topIdx, P, partial);
    pv_combine_kernel<<<Bd * Hd * NTOP, 64, 0, stream>>>(partial, invden, topIdx, out);
  } else {
    attn_update_kernel<<<Bd * Hd * NTOP, 256, 0, stream>>>(q, k, v, topIdx, out);
  }
}

// Round 8
// 108.657 us; speedup vs baseline: 3.8936x; 1.2411x over previous
//
#include <hip/hip_runtime.h>

#define Bd 4
#define Hd 8
#define Ld 2048
#define Dd 64
#define Ud 40
#define NTOP 40
#define NCHUNK 128
#define CSZ 16   // Ld / NCHUNK

#define NS 16     // k-splits for flash attention
#define FTILE 128 // Ld / NS keys per split
#define QSTR 68   // padded LDS stride (floats) for q rows
#define KSTR 68   // padded LDS stride (floats) for k/v rows
#define PSTR 132  // padded LDS stride for p rows

// ---------------------------------------------------------------------------
// Kernel 1: M[b,h,q] = max_u(dot(q, k[ridx[q,u]])) - sum_u(dot)/L
// One wave per (b,l) covering ALL 8 heads (ridx shared across b,h; K row for
// all heads is 2KB contiguous -> 2 coalesced dwordx4 loads per sample).
// ---------------------------------------------------------------------------
__global__ __launch_bounds__(256) void compute_M_kernel(
    const float* __restrict__ q, const float* __restrict__ k,
    const int* __restrict__ ridx, float* __restrict__ M) {
  const int nblk = Bd * Ld / 4;  // 2048 blocks, %8==0 -> bijective swizzle
  int orig = blockIdx.x;
  int bid = (orig & 7) * (nblk >> 3) + (orig >> 3);
  int gw = bid * 4 + (threadIdx.x >> 6);  // wave id = (b,l)
  int lane = threadIdx.x & 63;
  int hg = lane >> 3;  // head
  int s8 = lane & 7;   // 8-float slice within head row
  int b = gw >> 11;
  int l = gw & (Ld - 1);

  const float* qrow = q + ((size_t)b * Ld + l) * (Hd * Dd) + lane * 8;
  float4 q0 = *reinterpret_cast<const float4*>(qrow);
  float4 q1 = *reinterpret_cast<const float4*>(qrow + 4);

  int rv = 0;
  if (lane < Ud) rv = ridx[l * Ud + lane];

  const float* kb = k + (size_t)b * Ld * (Hd * Dd);

  float mx = -INFINITY, sm = 0.f;
#pragma unroll 8
  for (int u = 0; u < Ud; ++u) {
    int kidx = __shfl(rv, u);  // wave-uniform
    const float* kr = kb + (size_t)kidx * (Hd * Dd) + lane * 8;
    float4 k0 = *reinterpret_cast<const float4*>(kr);
    float4 k1 = *reinterpret_cast<const float4*>(kr + 4);
    float dot = q0.x * k0.x + q0.y * k0.y + q0.z * k0.z + q0.w * k0.w +
                q1.x * k1.x + q1.y * k1.y + q1.z * k1.z + q1.w * k1.w;
    dot += __shfl_xor(dot, 1);
    dot += __shfl_xor(dot, 2);
    dot += __shfl_xor(dot, 4);  // all 8 lanes of the head hold full dot
    mx = fmaxf(mx, dot);
    sm += dot;
  }
  if (s8 == 0)
    M[((size_t)b * Hd + hg) * Ld + l] = mx - sm * (1.0f / (float)Ld);
}

// ---------------------------------------------------------------------------
// Kernel 2: top-40 per (b,h), one wave, per-lane top-3 cache.
// ---------------------------------------------------------------------------
__global__ __launch_bounds__(64) void topk_kernel(const float* __restrict__ M,
                                                  int* __restrict__ topIdx) {
  int bh = blockIdx.x;
  int lane = threadIdx.x;
  const float* mrow = M + (size_t)bh * Ld;

  unsigned int key[32];
#pragma unroll
  for (int j = 0; j < 32; ++j) {
    unsigned int bits = __float_as_uint(mrow[lane + j * 64]);
    key[j] = (bits & 0x80000000u) ? ~bits : (bits | 0x80000000u);
  }

  const int ISENT = 1 << 30;
  unsigned int k0 = 0u, k1c = 0u, k2c = 0u;
  int i0 = ISENT, i1c = ISENT, i2c = ISENT;
#pragma unroll
  for (int j = 0; j < 32; ++j) {
    unsigned int kj = key[j];
    int idx = lane + j * 64;
    if (kj > k0) {
      k2c = k1c; i2c = i1c; k1c = k0; i1c = i0; k0 = kj; i0 = idx;
    } else if (kj > k1c) {
      k2c = k1c; i2c = i1c; k1c = kj; i1c = idx;
    } else if (kj > k2c) {
      k2c = kj; i2c = idx;
    }
  }

  for (int it = 0; it < NTOP; ++it) {
    unsigned int wk = k0;
    int wi = i0;
#pragma unroll
    for (int off = 1; off < 64; off <<= 1) {
      unsigned int ok = __shfl_xor(wk, off);
      int oi = __shfl_xor(wi, off);
      if (ok > wk || (ok == wk && oi < wi)) { wk = ok; wi = oi; }
    }
    if (lane == 0) topIdx[bh * NTOP + it] = wi;
    if (wi == i0) {
      k0 = k1c; i0 = i1c; k1c = k2c; i1c = i2c; k2c = 0u; i2c = ISENT;
      if (k0 == 0u) {
        i0 = ISENT; i1c = ISENT; i2c = ISENT;
#pragma unroll
        for (int j = 0; j < 32; ++j) {
          unsigned int kj = key[j];
          int idx = lane + j * 64;
          bool valid = (kj < wk) || (kj == wk && idx > wi);
          kj = valid ? kj : 0u;
          if (kj > k0) {
            k2c = k1c; i2c = i1c; k1c = k0; i1c = i0; k0 = kj; i0 = idx;
          } else if (kj > k1c) {
            k2c = k1c; i2c = i1c; k1c = kj; i1c = idx;
          } else if (kj > k2c) {
            k2c = kj; i2c = idx;
          }
        }
      }
    }
  }
}

// ---------------------------------------------------------------------------
// Kernel 3a/3b/3c: chunked cumsum of V along L.
// ---------------------------------------------------------------------------
__global__ void chunk_sums_kernel(const float* __restrict__ v,
                                  float* __restrict__ csum) {
  __shared__ float red[256];
  int blk = blockIdx.x;
  int c = blk % NCHUNK, bh = blk / NCHUNK;
  int b = bh >> 3, h = bh & 7;
  int d = threadIdx.x & 63, jg = threadIdx.x >> 6;
  int t0 = c * CSZ;
  float s = 0.f;
#pragma unroll
  for (int j = jg; j < CSZ; j += 4)
    s += v[(((size_t)b * Ld + t0 + j) * Hd + h) * Dd + d];
  red[threadIdx.x] = s;
  __syncthreads();
  if (jg == 0)
    csum[(size_t)blk * Dd + d] = red[d] + red[64 + d] + red[128 + d] + red[192 + d];
}

__global__ void scan_chunks_kernel(float* __restrict__ csum) {
  int bh = blockIdx.x;
  int d = threadIdx.x;
  float acc = 0.f;
#pragma unroll 8
  for (int c = 0; c < NCHUNK; ++c) {
    size_t i = ((size_t)bh * NCHUNK + c) * Dd + d;
    float s = csum[i];
    csum[i] = acc;
    acc += s;
  }
}

__global__ void cumsum_write_kernel(const float* __restrict__ v,
                                    const float* __restrict__ csum,
                                    float* __restrict__ out) {
  int blk = blockIdx.x;
  int c = blk % NCHUNK, bh = blk / NCHUNK;
  int b = bh >> 3, h = bh & 7;
  int d = threadIdx.x;
  float acc = csum[(size_t)blk * Dd + d];
  int t0 = c * CSZ;
#pragma unroll 4
  for (int j = 0; j < CSZ; ++j) {
    size_t idx = (((size_t)b * Ld + t0 + j) * Hd + h) * Dd + d;
    acc += v[idx];
    out[idx] = acc;
  }
}

// ---------------------------------------------------------------------------
// Kernel 4: fused split-K flash attention for the 40 selected rows.
// Grid: bh(32) x NS(16). Per block: stage Q-sel(40x64) + K-tile(128x64) in
// LDS; 5ux4k register-tile GEMM -> masked scaled scores in LDS p[40][128];
// per-row max/exp/sum (160 threads) overlapped with V-tile load into the K
// buffer; PV partial; emit Opart[40][64], m[40], sum[40] per split.
// ---------------------------------------------------------------------------
__global__ __launch_bounds__(256) void flash_attn_kernel(
    const float* __restrict__ q, const float* __restrict__ k,
    const float* __restrict__ v, const int* __restrict__ topIdx,
    float* __restrict__ Opart, float* __restrict__ mS,
    float* __restrict__ sS) {
  __shared__ float qs[NTOP * QSTR];
  __shared__ float ks[FTILE * KSTR];   // K tile, later reused for V tile
  __shared__ float p[NTOP * PSTR];
  __shared__ int ts[NTOP];
  int tid = threadIdx.x;
  int split = blockIdx.x % NS;
  int bh = blockIdx.x / NS;
  int b = bh >> 3, h = bh & 7;
  int k0 = split * FTILE;

  if (tid < NTOP) ts[tid] = topIdx[bh * NTOP + tid];
  __syncthreads();

  // stage Q-sel and K tile
  for (int i = tid; i < NTOP * 16; i += 256) {
    int u = i >> 4, ps = i & 15;
    float4 qv = reinterpret_cast<const float4*>(
        q + (((size_t)b * Ld + ts[u]) * Hd + h) * Dd)[ps];
    *reinterpret_cast<float4*>(&qs[u * QSTR + ps * 4]) = qv;
  }
  for (int i = tid; i < FTILE * 16; i += 256) {
    int r = i >> 4, ps = i & 15;
    float4 kv = reinterpret_cast<const float4*>(
        k + (((size_t)b * Ld + k0 + r) * Hd + h) * Dd)[ps];
    *reinterpret_cast<float4*>(&ks[r * KSTR + ps * 4]) = kv;
  }
  __syncthreads();

  // QK^T: 5u x 4k per thread
  int ug = tid & 7, kg = tid >> 3;
  int ub = ug * 5, kb = kg * 4;
  {
    float acc[5][4] = {};
    for (int dd = 0; dd < Dd; dd += 4) {
      float4 kv[4], qv[5];
#pragma unroll
      for (int i = 0; i < 4; ++i)
        kv[i] = *reinterpret_cast<const float4*>(&ks[(kb + i) * KSTR + dd]);
#pragma unroll
      for (int i = 0; i < 5; ++i)
        qv[i] = *reinterpret_cast<const float4*>(&qs[(ub + i) * QSTR + dd]);
#pragma unroll
      for (int ui = 0; ui < 5; ++ui)
#pragma unroll
        for (int ki = 0; ki < 4; ++ki)
          acc[ui][ki] += qv[ui].x * kv[ki].x + qv[ui].y * kv[ki].y +
                         qv[ui].z * kv[ki].z + qv[ui].w * kv[ki].w;
    }
#pragma unroll
    for (int ui = 0; ui < 5; ++ui) {
      int u = ub + ui;
      int t = ts[u];
      float4 o;
      o.x = (k0 + kb + 0 <= t) ? acc[ui][0] * 0.125f : -INFINITY;
      o.y = (k0 + kb + 1 <= t) ? acc[ui][1] * 0.125f : -INFINITY;
      o.z = (k0 + kb + 2 <= t) ? acc[ui][2] * 0.125f : -INFINITY;
      o.w = (k0 + kb + 3 <= t) ? acc[ui][3] * 0.125f : -INFINITY;
      *reinterpret_cast<float4*>(&p[u * PSTR + kb]) = o;
    }
  }
  __syncthreads();

  // V tile load (into ks) overlapped with per-row softmax stats (160 thr)
  for (int i = tid; i < FTILE * 16; i += 256) {
    int r = i >> 4, ps = i & 15;
    float4 vv = reinterpret_cast<const float4*>(
        v + (((size_t)b * Ld + k0 + r) * Hd + h) * Dd)[ps];
    *reinterpret_cast<float4*>(&ks[r * KSTR + ps * 4]) = vv;
  }
  if (tid < NTOP * 4) {
    int u = tid >> 2, l4 = tid & 3;
    float* pr = p + u * PSTR;
    float mx = -1e30f;
#pragma unroll 8
    for (int j = l4; j < FTILE; j += 4) mx = fmaxf(mx, pr[j]);
    mx = fmaxf(mx, __shfl_xor(mx, 1));
    mx = fmaxf(mx, __shfl_xor(mx, 2));
    float sum = 0.f;
#pragma unroll 8
    for (int j = l4; j < FTILE; j += 4) {
      float pe = __expf(pr[j] - mx);  // -inf - (-1e30) = -inf -> 0, no NaN
      pr[j] = pe;
      sum += pe;
    }
    sum += __shfl_xor(sum, 1);
    sum += __shfl_xor(sum, 2);
    if (l4 == 0) {
      mS[((size_t)bh * NS + split) * NTOP + u] = mx;
      sS[((size_t)bh * NS + split) * NTOP + u] = sum;
    }
  }
  __syncthreads();

  // PV: thread (ug2 = tid>>5 -> 5 u-rows, dg = tid&31 -> 2 d-cols)
  int ug2 = tid >> 5, dg = tid & 31;
  int ub2 = ug2 * 5, d2 = dg * 2;
  float acc[5][2] = {};
#pragma unroll 4
  for (int kk = 0; kk < FTILE; ++kk) {
    float2 vv = *reinterpret_cast<const float2*>(&ks[kk * KSTR + d2]);
#pragma unroll
    for (int i = 0; i < 5; ++i) {
      float pe = p[(ub2 + i) * PSTR + kk];  // broadcast across 32 lanes
      acc[i][0] += pe * vv.x;
      acc[i][1] += pe * vv.y;
    }
  }
  float* ob = Opart + ((size_t)bh * NS + split) * (NTOP * Dd);
#pragma unroll
  for (int i = 0; i < 5; ++i)
    *reinterpret_cast<float2*>(&ob[(ub2 + i) * Dd + d2]) =
        make_float2(acc[i][0], acc[i][1]);
}

// ---------------------------------------------------------------------------
// Kernel 5: LSE combine across NS splits + scatter-overwrite output rows.
// ---------------------------------------------------------------------------
__global__ __launch_bounds__(64) void flash_combine_kernel(
    const float* __restrict__ Opart, const float* __restrict__ mS,
    const float* __restrict__ sS, const int* __restrict__ topIdx,
    float* __restrict__ out) {
  int row = blockIdx.x;  // bh*NTOP + u
  int u = row % NTOP, bh = row / NTOP;
  int b = bh >> 3, h = bh & 7;
  int d = threadIdx.x;
  int t = topIdx[row];

  float mg = -1e30f;
#pragma unroll
  for (int s = 0; s < NS; ++s)
    mg = fmaxf(mg, mS[((size_t)bh * NS + s) * NTOP + u]);
  float den = 0.f, o = 0.f;
#pragma unroll
  for (int s = 0; s < NS; ++s) {
    float w = __expf(mS[((size_t)bh * NS + s) * NTOP + u] - mg);
    den += w * sS[((size_t)bh * NS + s) * NTOP + u];
    o += w * Opart[(((size_t)bh * NS + s) * NTOP + u) * Dd + d];
  }
  out[(((size_t)b * Ld + t) * Hd + h) * Dd + d] = o / den;
}

// ---------------------------------------------------------------------------
// Fallback attention kernel if ws is too small.
// ---------------------------------------------------------------------------
__global__ void attn_update_kernel(const float* __restrict__ q,
                                   const float* __restrict__ k,
                                   const float* __restrict__ v,
                                   const int* __restrict__ topIdx,
                                   float* __restrict__ out) {
  __shared__ float sc[Ld];
  __shared__ float qs[Dd];
  __shared__ float red[256];
  int tid = threadIdx.x;
  int bh = blockIdx.x / NTOP;
  int b = bh >> 3, h = bh & 7;
  int t = topIdx[blockIdx.x];

  if (tid < Dd) qs[tid] = q[(((size_t)b * Ld + t) * Hd + h) * Dd + tid];
  __syncthreads();

  int nk = t + 1;
  const float4* qv4 = reinterpret_cast<const float4*>(qs);
  float lmax = -INFINITY;
  for (int kk = tid; kk < nk; kk += 256) {
    const float4* kr = reinterpret_cast<const float4*>(
        k + (((size_t)b * Ld + kk) * Hd + h) * Dd);
    float dot = 0.f;
#pragma unroll
    for (int j = 0; j < Dd / 4; ++j) {
      float4 a = qv4[j];
      float4 bb = kr[j];
      dot += a.x * bb.x + a.y * bb.y + a.z * bb.z + a.w * bb.w;
    }
    dot *= 0.125f;
    sc[kk] = dot;
    lmax = fmaxf(lmax, dot);
  }
  red[tid] = lmax;
  __syncthreads();
  for (int s = 128; s; s >>= 1) {
    if (tid < s) red[tid] = fmaxf(red[tid], red[tid + s]);
    __syncthreads();
  }
  float m = red[0];
  __syncthreads();
  float lsum = 0.f;
  for (int kk = tid; kk < nk; kk += 256) {
    float pp = __expf(sc[kk] - m);
    sc[kk] = pp;
    lsum += pp;
  }
  red[tid] = lsum;
  __syncthreads();
  for (int s = 128; s; s >>= 1) {
    if (tid < s) red[tid] += red[tid + s];
    __syncthreads();
  }
  float inv_denom = 1.0f / red[0];
  __syncthreads();
  int d = tid & 63, kg = tid >> 6;
  float acc = 0.f;
  for (int kk = kg; kk < nk; kk += 4)
    acc += sc[kk] * v[(((size_t)b * Ld + kk) * Hd + h) * Dd + d];
  red[tid] = acc;
  __syncthreads();
  if (kg == 0) {
    float r = red[d] + red[64 + d] + red[128 + d] + red[192 + d];
    out[(((size_t)b * Ld + t) * Hd + h) * Dd + d] = r * inv_denom;
  }
}

// ---------------------------------------------------------------------------
extern "C" void kernel_launch(void* const* d_in, const int* in_sizes, int n_in,
                              void* d_out, int out_size, void* d_ws,
                              size_t ws_size, hipStream_t stream) {
  const float* q = (const float*)d_in[0];
  const float* k = (const float*)d_in[1];
  const float* v = (const float*)d_in[2];
  const int* ridx = (const int*)d_in[4];
  float* out = (float*)d_out;

  char* ws = (char*)d_ws;
  float* M = (float*)(ws + 0);              // 262144
  int* topIdx = (int*)(ws + 262144);        //   5120
  float* csum = (float*)(ws + 272384);      // 1048576
  float* Opart = (float*)(ws + 3942400);    // 32*16*40*64*4 = 5242880
  float* mS = (float*)(ws + 9185280);       // 32*16*40*4    =   81920
  float* sS = (float*)(ws + 9267200);       //                   81920
  const size_t need_new = 9349120;

  compute_M_kernel<<<Bd * Ld / 4, 256, 0, stream>>>(q, k, ridx, M);
  topk_kernel<<<Bd * Hd, 64, 0, stream>>>(M, topIdx);
  chunk_sums_kernel<<<Bd * Hd * NCHUNK, 256, 0, stream>>>(v, csum);
  scan_chunks_kernel<<<Bd * Hd, 64, 0, stream>>>(csum);
  cumsum_write_kernel<<<Bd * Hd * NCHUNK, 64, 0, stream>>>(v, csum, out);

  if (ws_size >= need_new) {
    flash_attn_kernel<<<Bd * Hd * NS, 256, 0, stream>>>(q, k, v, topIdx,
                                                        Opart, mS, sS);
    flash_combine_kernel<<<Bd * Hd * NTOP, 64, 0, stream>>>(Opart, mS, sS,
                                                            topIdx, out);
  } else {
    attn_update_kernel<<<Bd * Hd * NTOP, 256, 0, stream>>>(q, k, v, topIdx, out);
  }
}

// Round 9
// 94.768 us; speedup vs baseline: 4.4642x; 1.1466x over previous
//
#include <hip/hip_runtime.h>

#define Bd 4
#define Hd 8
#define Ld 2048
#define Dd 64
#define Ud 40
#define NTOP 40
#define NCHUNK 64
#define CSZ 32   // Ld / NCHUNK

#define NS 16     // k-splits for flash attention
#define FTILE 128 // Ld / NS keys per split
#define QSTR 68   // padded LDS stride (floats) for q rows
#define KSTR 68   // padded LDS stride (floats) for k/v rows
#define PSTR 132  // padded LDS stride for p rows

// ---------------------------------------------------------------------------
// Phase 1: role A (blocks 0..2047)  = compute_M  (one wave per (b,l), all 8
//          heads; 2KB-contiguous K-row gathers; XCD swizzle).
//          role B (blocks 2048..4095) = chunk_sums of V (chunk = 32 rows).
// ---------------------------------------------------------------------------
__global__ __launch_bounds__(256) void phase1_kernel(
    const float* __restrict__ q, const float* __restrict__ k,
    const float* __restrict__ v, const int* __restrict__ ridx,
    float* __restrict__ M, float* __restrict__ csum) {
  __shared__ float red[256];
  int tid = threadIdx.x;
  if (blockIdx.x < 2048) {
    // ---- compute_M ----
    const int nblk = 2048;
    int orig = blockIdx.x;
    int bid = (orig & 7) * (nblk >> 3) + (orig >> 3);
    int gw = bid * 4 + (tid >> 6);
    int lane = tid & 63;
    int hg = lane >> 3;
    int s8 = lane & 7;
    int b = gw >> 11;
    int l = gw & (Ld - 1);

    const float* qrow = q + ((size_t)b * Ld + l) * (Hd * Dd) + lane * 8;
    float4 q0 = *reinterpret_cast<const float4*>(qrow);
    float4 q1 = *reinterpret_cast<const float4*>(qrow + 4);

    int rv = 0;
    if (lane < Ud) rv = ridx[l * Ud + lane];
    const float* kb = k + (size_t)b * Ld * (Hd * Dd);

    float mx = -INFINITY, sm = 0.f;
#pragma unroll 8
    for (int u = 0; u < Ud; ++u) {
      int kidx = __shfl(rv, u);
      const float* kr = kb + (size_t)kidx * (Hd * Dd) + lane * 8;
      float4 k0 = *reinterpret_cast<const float4*>(kr);
      float4 k1 = *reinterpret_cast<const float4*>(kr + 4);
      float dot = q0.x * k0.x + q0.y * k0.y + q0.z * k0.z + q0.w * k0.w +
                  q1.x * k1.x + q1.y * k1.y + q1.z * k1.z + q1.w * k1.w;
      dot += __shfl_xor(dot, 1);
      dot += __shfl_xor(dot, 2);
      dot += __shfl_xor(dot, 4);
      mx = fmaxf(mx, dot);
      sm += dot;
    }
    if (s8 == 0)
      M[((size_t)b * Hd + hg) * Ld + l] = mx - sm * (1.0f / (float)Ld);
  } else {
    // ---- chunk sums of V ----
    int n = blockIdx.x - 2048;  // 0..2047 = bh*NCHUNK + c
    int c = n & (NCHUNK - 1), bh = n >> 6;
    int b = bh >> 3, h = bh & 7;
    int d = tid & 63, jg = tid >> 6;
    int t0 = c * CSZ;
    float s = 0.f;
#pragma unroll
    for (int j = jg; j < CSZ; j += 4)
      s += v[(((size_t)b * Ld + t0 + j) * Hd + h) * Dd + d];
    red[tid] = s;
    __syncthreads();
    if (jg == 0)
      csum[(size_t)n * Dd + d] =
          red[d] + red[64 + d] + red[128 + d] + red[192 + d];
  }
}

// ---------------------------------------------------------------------------
// Phase 2: role A (blocks 0..31) = top-40 per (b,h) (per-lane top-3 cache);
//          role B (blocks 32..63) = exclusive scan of chunk sums.
// ---------------------------------------------------------------------------
__global__ __launch_bounds__(64) void phase2_kernel(const float* __restrict__ M,
                                                    int* __restrict__ topIdx,
                                                    float* __restrict__ csum) {
  int lane = threadIdx.x;
  if (blockIdx.x < 32) {
    int bh = blockIdx.x;
    const float* mrow = M + (size_t)bh * Ld;

    unsigned int key[32];
#pragma unroll
    for (int j = 0; j < 32; ++j) {
      unsigned int bits = __float_as_uint(mrow[lane + j * 64]);
      key[j] = (bits & 0x80000000u) ? ~bits : (bits | 0x80000000u);
    }

    const int ISENT = 1 << 30;
    unsigned int k0 = 0u, k1c = 0u, k2c = 0u;
    int i0 = ISENT, i1c = ISENT, i2c = ISENT;
#pragma unroll
    for (int j = 0; j < 32; ++j) {
      unsigned int kj = key[j];
      int idx = lane + j * 64;
      if (kj > k0) {
        k2c = k1c; i2c = i1c; k1c = k0; i1c = i0; k0 = kj; i0 = idx;
      } else if (kj > k1c) {
        k2c = k1c; i2c = i1c; k1c = kj; i1c = idx;
      } else if (kj > k2c) {
        k2c = kj; i2c = idx;
      }
    }

    for (int it = 0; it < NTOP; ++it) {
      unsigned int wk = k0;
      int wi = i0;
#pragma unroll
      for (int off = 1; off < 64; off <<= 1) {
        unsigned int ok = __shfl_xor(wk, off);
        int oi = __shfl_xor(wi, off);
        if (ok > wk || (ok == wk && oi < wi)) { wk = ok; wi = oi; }
      }
      if (lane == 0) topIdx[bh * NTOP + it] = wi;
      if (wi == i0) {
        k0 = k1c; i0 = i1c; k1c = k2c; i1c = i2c; k2c = 0u; i2c = ISENT;
        if (k0 == 0u) {
          i0 = ISENT; i1c = ISENT; i2c = ISENT;
#pragma unroll
          for (int j = 0; j < 32; ++j) {
            unsigned int kj = key[j];
            int idx = lane + j * 64;
            bool valid = (kj < wk) || (kj == wk && idx > wi);
            kj = valid ? kj : 0u;
            if (kj > k0) {
              k2c = k1c; i2c = i1c; k1c = k0; i1c = i0; k0 = kj; i0 = idx;
            } else if (kj > k1c) {
              k2c = k1c; i2c = i1c; k1c = kj; i1c = idx;
            } else if (kj > k2c) {
              k2c = kj; i2c = idx;
            }
          }
        }
      }
    }
  } else {
    int bh = blockIdx.x - 32;
    float acc = 0.f;
#pragma unroll 8
    for (int c = 0; c < NCHUNK; ++c) {
      size_t i = ((size_t)bh * NCHUNK + c) * Dd + lane;
      float s = csum[i];
      csum[i] = acc;
      acc += s;
    }
  }
}

// ---------------------------------------------------------------------------
// Phase 3: role A (blocks 0..511)  = fused split-K flash attention
//          role B (blocks 512..1023) = cumsum write (wave per 32-row chunk).
// ---------------------------------------------------------------------------
__global__ __launch_bounds__(256) void phase3_kernel(
    const float* __restrict__ q, const float* __restrict__ k,
    const float* __restrict__ v, const int* __restrict__ topIdx,
    const float* __restrict__ csum, float* __restrict__ out,
    float* __restrict__ Opart, float* __restrict__ mS,
    float* __restrict__ sS) {
  __shared__ float qs[NTOP * QSTR];
  __shared__ float ks[FTILE * KSTR];
  __shared__ float p[NTOP * PSTR];
  __shared__ int ts[NTOP];
  int tid = threadIdx.x;

  if (blockIdx.x >= 512) {
    // ---- cumsum write: 4 waves x one 32-row chunk each ----
    int m = blockIdx.x - 512;  // 0..511
    int lane = tid & 63, w = tid >> 6;
    int blk = m * 4 + w;  // 0..2047 = bh*NCHUNK + c
    int c = blk & (NCHUNK - 1), bh = blk >> 6;
    int b = bh >> 3, h = bh & 7;
    float acc = csum[(size_t)blk * Dd + lane];
    int t0 = c * CSZ;
    const float* vp = v + (((size_t)b * Ld + t0) * Hd + h) * Dd + lane;
    float* op = out + (((size_t)b * Ld + t0) * Hd + h) * Dd + lane;
#pragma unroll 8
    for (int j = 0; j < CSZ; ++j) {
      acc += vp[(size_t)j * (Hd * Dd)];
      op[(size_t)j * (Hd * Dd)] = acc;
    }
    return;
  }

  // ---- flash attention split ----
  int split = blockIdx.x % NS;
  int bh = blockIdx.x / NS;
  int b = bh >> 3, h = bh & 7;
  int k0 = split * FTILE;

  if (tid < NTOP) ts[tid] = topIdx[bh * NTOP + tid];
  __syncthreads();

  for (int i = tid; i < NTOP * 16; i += 256) {
    int u = i >> 4, ps = i & 15;
    float4 qv = reinterpret_cast<const float4*>(
        q + (((size_t)b * Ld + ts[u]) * Hd + h) * Dd)[ps];
    *reinterpret_cast<float4*>(&qs[u * QSTR + ps * 4]) = qv;
  }
  for (int i = tid; i < FTILE * 16; i += 256) {
    int r = i >> 4, ps = i & 15;
    float4 kv = reinterpret_cast<const float4*>(
        k + (((size_t)b * Ld + k0 + r) * Hd + h) * Dd)[ps];
    *reinterpret_cast<float4*>(&ks[r * KSTR + ps * 4]) = kv;
  }
  __syncthreads();

  int ug = tid & 7, kg = tid >> 3;
  int ub = ug * 5, kb = kg * 4;
  {
    float acc[5][4] = {};
    for (int dd = 0; dd < Dd; dd += 4) {
      float4 kv[4], qv[5];
#pragma unroll
      for (int i = 0; i < 4; ++i)
        kv[i] = *reinterpret_cast<const float4*>(&ks[(kb + i) * KSTR + dd]);
#pragma unroll
      for (int i = 0; i < 5; ++i)
        qv[i] = *reinterpret_cast<const float4*>(&qs[(ub + i) * QSTR + dd]);
#pragma unroll
      for (int ui = 0; ui < 5; ++ui)
#pragma unroll
        for (int ki = 0; ki < 4; ++ki)
          acc[ui][ki] += qv[ui].x * kv[ki].x + qv[ui].y * kv[ki].y +
                         qv[ui].z * kv[ki].z + qv[ui].w * kv[ki].w;
    }
#pragma unroll
    for (int ui = 0; ui < 5; ++ui) {
      int u = ub + ui;
      int t = ts[u];
      float4 o;
      o.x = (k0 + kb + 0 <= t) ? acc[ui][0] * 0.125f : -INFINITY;
      o.y = (k0 + kb + 1 <= t) ? acc[ui][1] * 0.125f : -INFINITY;
      o.z = (k0 + kb + 2 <= t) ? acc[ui][2] * 0.125f : -INFINITY;
      o.w = (k0 + kb + 3 <= t) ? acc[ui][3] * 0.125f : -INFINITY;
      *reinterpret_cast<float4*>(&p[u * PSTR + kb]) = o;
    }
  }
  __syncthreads();

  // V tile load (into ks) overlapped with per-row softmax stats
  for (int i = tid; i < FTILE * 16; i += 256) {
    int r = i >> 4, ps = i & 15;
    float4 vv = reinterpret_cast<const float4*>(
        v + (((size_t)b * Ld + k0 + r) * Hd + h) * Dd)[ps];
    *reinterpret_cast<float4*>(&ks[r * KSTR + ps * 4]) = vv;
  }
  if (tid < NTOP * 4) {
    int u = tid >> 2, l4 = tid & 3;
    float* pr = p + u * PSTR;
    float mx = -1e30f;
#pragma unroll 8
    for (int j = l4; j < FTILE; j += 4) mx = fmaxf(mx, pr[j]);
    mx = fmaxf(mx, __shfl_xor(mx, 1));
    mx = fmaxf(mx, __shfl_xor(mx, 2));
    float sum = 0.f;
#pragma unroll 8
    for (int j = l4; j < FTILE; j += 4) {
      float pe = __expf(pr[j] - mx);
      pr[j] = pe;
      sum += pe;
    }
    sum += __shfl_xor(sum, 1);
    sum += __shfl_xor(sum, 2);
    if (l4 == 0) {
      mS[((size_t)bh * NS + split) * NTOP + u] = mx;
      sS[((size_t)bh * NS + split) * NTOP + u] = sum;
    }
  }
  __syncthreads();

  int ug2 = tid >> 5, dg = tid & 31;
  int ub2 = ug2 * 5, d2 = dg * 2;
  float acc[5][2] = {};
#pragma unroll 4
  for (int kk = 0; kk < FTILE; ++kk) {
    float2 vv = *reinterpret_cast<const float2*>(&ks[kk * KSTR + d2]);
#pragma unroll
    for (int i = 0; i < 5; ++i) {
      float pe = p[(ub2 + i) * PSTR + kk];
      acc[i][0] += pe * vv.x;
      acc[i][1] += pe * vv.y;
    }
  }
  float* ob = Opart + ((size_t)bh * NS + split) * (NTOP * Dd);
#pragma unroll
  for (int i = 0; i < 5; ++i)
    *reinterpret_cast<float2*>(&ob[(ub2 + i) * Dd + d2]) =
        make_float2(acc[i][0], acc[i][1]);
}

// ---------------------------------------------------------------------------
// Phase 4: LSE combine across NS splits + scatter-overwrite output rows.
// ---------------------------------------------------------------------------
__global__ __launch_bounds__(64) void flash_combine_kernel(
    const float* __restrict__ Opart, const float* __restrict__ mS,
    const float* __restrict__ sS, const int* __restrict__ topIdx,
    float* __restrict__ out) {
  int row = blockIdx.x;
  int u = row % NTOP, bh = row / NTOP;
  int b = bh >> 3, h = bh & 7;
  int d = threadIdx.x;
  int t = topIdx[row];

  float mg = -1e30f;
#pragma unroll
  for (int s = 0; s < NS; ++s)
    mg = fmaxf(mg, mS[((size_t)bh * NS + s) * NTOP + u]);
  float den = 0.f, o = 0.f;
#pragma unroll
  for (int s = 0; s < NS; ++s) {
    float w = __expf(mS[((size_t)bh * NS + s) * NTOP + u] - mg);
    den += w * sS[((size_t)bh * NS + s) * NTOP + u];
    o += w * Opart[(((size_t)bh * NS + s) * NTOP + u) * Dd + d];
  }
  out[(((size_t)b * Ld + t) * Hd + h) * Dd + d] = o / den;
}

// ---------------------------------------------------------------------------
// Fallback pieces (ws too small): standalone cumsum write + simple attention.
// ---------------------------------------------------------------------------
__global__ void cumsum_write_kernel(const float* __restrict__ v,
                                    const float* __restrict__ csum,
                                    float* __restrict__ out) {
  int blk = blockIdx.x;
  int c = blk & (NCHUNK - 1), bh = blk >> 6;
  int b = bh >> 3, h = bh & 7;
  int d = threadIdx.x;
  float acc = csum[(size_t)blk * Dd + d];
  int t0 = c * CSZ;
#pragma unroll 8
  for (int j = 0; j < CSZ; ++j) {
    size_t idx = (((size_t)b * Ld + t0 + j) * Hd + h) * Dd + d;
    acc += v[idx];
    out[idx] = acc;
  }
}

__global__ void attn_update_kernel(const float* __restrict__ q,
                                   const float* __restrict__ k,
                                   const float* __restrict__ v,
                                   const int* __restrict__ topIdx,
                                   float* __restrict__ out) {
  __shared__ float sc[Ld];
  __shared__ float qs[Dd];
  __shared__ float red[256];
  int tid = threadIdx.x;
  int bh = blockIdx.x / NTOP;
  int b = bh >> 3, h = bh & 7;
  int t = topIdx[blockIdx.x];

  if (tid < Dd) qs[tid] = q[(((size_t)b * Ld + t) * Hd + h) * Dd + tid];
  __syncthreads();

  int nk = t + 1;
  const float4* qv4 = reinterpret_cast<const float4*>(qs);
  float lmax = -INFINITY;
  for (int kk = tid; kk < nk; kk += 256) {
    const float4* kr = reinterpret_cast<const float4*>(
        k + (((size_t)b * Ld + kk) * Hd + h) * Dd);
    float dot = 0.f;
#pragma unroll
    for (int j = 0; j < Dd / 4; ++j) {
      float4 a = qv4[j];
      float4 bb = kr[j];
      dot += a.x * bb.x + a.y * bb.y + a.z * bb.z + a.w * bb.w;
    }
    dot *= 0.125f;
    sc[kk] = dot;
    lmax = fmaxf(lmax, dot);
  }
  red[tid] = lmax;
  __syncthreads();
  for (int s = 128; s; s >>= 1) {
    if (tid < s) red[tid] = fmaxf(red[tid], red[tid + s]);
    __syncthreads();
  }
  float m = red[0];
  __syncthreads();
  float lsum = 0.f;
  for (int kk = tid; kk < nk; kk += 256) {
    float pp = __expf(sc[kk] - m);
    sc[kk] = pp;
    lsum += pp;
  }
  red[tid] = lsum;
  __syncthreads();
  for (int s = 128; s; s >>= 1) {
    if (tid < s) red[tid] += red[tid + s];
    __syncthreads();
  }
  float inv_denom = 1.0f / red[0];
  __syncthreads();
  int d = tid & 63, kg = tid >> 6;
  float acc = 0.f;
  for (int kk = kg; kk < nk; kk += 4)
    acc += sc[kk] * v[(((size_t)b * Ld + kk) * Hd + h) * Dd + d];
  red[tid] = acc;
  __syncthreads();
  if (kg == 0) {
    float r = red[d] + red[64 + d] + red[128 + d] + red[192 + d];
    out[(((size_t)b * Ld + t) * Hd + h) * Dd + d] = r * inv_denom;
  }
}

// ---------------------------------------------------------------------------
extern "C" void kernel_launch(void* const* d_in, const int* in_sizes, int n_in,
                              void* d_out, int out_size, void* d_ws,
                              size_t ws_size, hipStream_t stream) {
  const float* q = (const float*)d_in[0];
  const float* k = (const float*)d_in[1];
  const float* v = (const float*)d_in[2];
  const int* ridx = (const int*)d_in[4];
  float* out = (float*)d_out;

  char* ws = (char*)d_ws;
  float* M = (float*)(ws + 0);              // 262144
  int* topIdx = (int*)(ws + 262144);        //   5120
  float* csum = (float*)(ws + 272384);      // 2048*64*4 = 524288
  float* Opart = (float*)(ws + 3942400);    // 32*16*40*64*4 = 5242880
  float* mS = (float*)(ws + 9185280);       //   81920
  float* sS = (float*)(ws + 9267200);       //   81920
  const size_t need_new = 9349120;

  phase1_kernel<<<4096, 256, 0, stream>>>(q, k, v, ridx, M, csum);
  phase2_kernel<<<64, 64, 0, stream>>>(M, topIdx, csum);

  if (ws_size >= need_new) {
    phase3_kernel<<<1024, 256, 0, stream>>>(q, k, v, topIdx, csum, out, Opart,
                                            mS, sS);
    flash_combine_kernel<<<Bd * Hd * NTOP, 64, 0, stream>>>(Opart, mS, sS,
                                                            topIdx, out);
  } else {
    cumsum_write_kernel<<<Bd * Hd * NCHUNK, 64, 0, stream>>>(v, csum, out);
    attn_update_kernel<<<Bd * Hd * NTOP, 256, 0, stream>>>(q, k, v, topIdx,
                                                           out);
  }
}